// Round 16
// baseline (1235.575 us; speedup 1.0000x reference)
//
#include <hip/hip_runtime.h>
#include <hip/hip_bf16.h>

// Qwen3.5 GatedDeltaNet: B=2, T=4096, D=2048, NV=32, NK=16, DK=DV=128, KC=4
// Round 16: gemm256 BK 64->32 (LDS 128->64 KiB => 2 blocks/CU: barrier drains
// covered by the co-resident block's waves). conv_chunk 4 tokens/block
// (7 row-loads / 4 outputs). Everything else = round 15 (best, 1081 us).

typedef __attribute__((ext_vector_type(8))) short short8;
typedef __attribute__((ext_vector_type(4))) float f32x4;
typedef unsigned short us;

static __device__ __forceinline__ us f2b(float f) {
  __hip_bfloat16 h = __float2bfloat16(f);
  return __builtin_bit_cast(us, h);
}
static __device__ __forceinline__ float b2f(us u) {
  return __bfloat162float(__builtin_bit_cast(__hip_bfloat16, u));
}
// barrier that publishes LDS (lgkmcnt) but leaves global loads/stores in flight
static __device__ __forceinline__ void bar_lds() {
  asm volatile("s_waitcnt lgkmcnt(0)" ::: "memory");
  __builtin_amdgcn_s_barrier();
}

// ---------------- fp32 -> bf16 elementwise ----------------
__global__ __launch_bounds__(256) void cvt_f32_bf16(const float* __restrict__ in,
    us* __restrict__ out, long n4) {
  long i = (long)blockIdx.x * 256 + threadIdx.x;
  long stride = (long)gridDim.x * 256;
  for (; i < n4; i += stride) {
    float4 f = reinterpret_cast<const float4*>(in)[i];
    ushort4 u;
    u.x = f2b(f.x); u.y = f2b(f.y); u.z = f2b(f.z); u.w = f2b(f.w);
    reinterpret_cast<ushort4*>(out)[i] = u;
  }
}

// ------- fp32 [K][Nfull] (col slice) -> bf16 [N][K] transpose, 64x64 tiles -------
__global__ __launch_bounds__(256) void transpose_cvt(const float* __restrict__ in,
    us* __restrict__ out, int K, int N, int Nfull, int coloff, int row_off) {
  __shared__ float tile[64][65];
  int tid = threadIdx.x;
  int n0 = blockIdx.x * 64, k0 = blockIdx.y * 64;
  int tx = tid & 15, ty = tid >> 4;
#pragma unroll
  for (int r = 0; r < 4; ++r) {
    int kk = k0 + ty + r * 16, nn = n0 + tx * 4;
    float4 v = make_float4(0.f, 0.f, 0.f, 0.f);
    if (kk < K && nn < N)
      v = *reinterpret_cast<const float4*>(in + (size_t)kk * Nfull + coloff + nn);
    tile[ty + r * 16][tx * 4 + 0] = v.x;
    tile[ty + r * 16][tx * 4 + 1] = v.y;
    tile[ty + r * 16][tx * 4 + 2] = v.z;
    tile[ty + r * 16][tx * 4 + 3] = v.w;
  }
  __syncthreads();
#pragma unroll
  for (int g = 0; g < 2; ++g) {
    int s = tid + g * 256;
    int nn = s >> 3, ks = (s & 7) * 8;
    if (n0 + nn < N && k0 + ks < K) {
      us ov[8];
#pragma unroll
      for (int i = 0; i < 8; ++i) ov[i] = f2b(tile[ks + i][nn]);
      *reinterpret_cast<uint4*>(out + (size_t)(n0 + nn + row_off) * K + k0 + ks) =
          *reinterpret_cast<uint4*>(ov);
    }
  }
}

// ========== 256x256 8-wave double-buffered TN GEMM, BK=32 (64 KiB LDS) ==========
// LDS slot swizzle (16B units, 4 slots/row): phys = slot ^ ((row>>1)&3);
// source pre-swizzled, reads XOR the same.
template <bool BF16OUT>
__global__ __launch_bounds__(512, 1) void gemm256(const us* __restrict__ A,
    const us* __restrict__ B, void* __restrict__ Cout, int K, int ldC) {
  __shared__ us Abuf[2][256 * 32];
  __shared__ us Bbuf[2][256 * 32];
  int tid = threadIdx.x, w = tid >> 6, lane = tid & 63;
  int wr = w >> 2, wc = w & 3;
  int fr = lane & 15, j4 = lane >> 4;
  int lin = blockIdx.y * gridDim.x + blockIdx.x;
  int nwg = gridDim.x * gridDim.y;
  int wg = (lin & 7) * (nwg >> 3) + (lin >> 3);
  int bx = wg % gridDim.x, by = wg / gridDim.x;
  size_t bm = (size_t)bx * 256, bn = (size_t)by * 256;

  const us *aG[2], *bG[2];
  us *aL[2][2], *bL[2][2];
#pragma unroll
  for (int u = 0; u < 2; ++u) {
    int idx = u * 512 + tid;
    int row = idx >> 2, sl = idx & 3;
    int sg = (sl ^ ((row >> 1) & 3)) * 8;
    aG[u] = A + (bm + row) * K + sg;
    bG[u] = B + (bn + row) * K + sg;
    int lbase = (u * 128 + w * 16) * 32;
#pragma unroll
    for (int bf = 0; bf < 2; ++bf) {
      aL[bf][u] = &Abuf[bf][lbase];
      bL[bf][u] = &Bbuf[bf][lbase];
    }
  }

  f32x4 acc[8][4] = {};
#pragma unroll
  for (int u = 0; u < 2; ++u) {
    __builtin_amdgcn_global_load_lds((const void*)aG[u], (void*)aL[0][u], 16, 0, 0);
    __builtin_amdgcn_global_load_lds((const void*)bG[u], (void*)bL[0][u], 16, 0, 0);
  }
  __syncthreads();

  int nt = K >> 5;
  for (int t = 0; t < nt; ++t) {
    int cur = t & 1, nxt = cur ^ 1;
    const us* Ac = Abuf[cur];
    const us* Bc = Bbuf[cur];
    int kt1 = (t + 1) << 5;
    bool more = (t + 1 < nt);
#pragma unroll
    for (int q = 0; q < 4; ++q) {
      if (more) {
        if (q == 0)
          __builtin_amdgcn_global_load_lds((const void*)(aG[0] + kt1), (void*)aL[nxt][0], 16, 0, 0);
        else if (q == 1)
          __builtin_amdgcn_global_load_lds((const void*)(aG[1] + kt1), (void*)aL[nxt][1], 16, 0, 0);
        else if (q == 2)
          __builtin_amdgcn_global_load_lds((const void*)(bG[0] + kt1), (void*)bL[nxt][0], 16, 0, 0);
        else
          __builtin_amdgcn_global_load_lds((const void*)(bG[1] + kt1), (void*)bL[nxt][1], 16, 0, 0);
      }
      short8 a0, a1, bfv[4];
      int Ra0 = wr * 128 + 2 * q * 16 + fr;
      int Ra1 = Ra0 + 16;
      a0 = *reinterpret_cast<const short8*>(&Ac[Ra0 * 32 + ((j4 ^ ((Ra0 >> 1) & 3)) * 8)]);
      a1 = *reinterpret_cast<const short8*>(&Ac[Ra1 * 32 + ((j4 ^ ((Ra1 >> 1) & 3)) * 8)]);
#pragma unroll
      for (int fj = 0; fj < 4; ++fj) {
        int Rb = wc * 64 + fj * 16 + fr;
        bfv[fj] = *reinterpret_cast<const short8*>(&Bc[Rb * 32 + ((j4 ^ ((Rb >> 1) & 3)) * 8)]);
      }
      __builtin_amdgcn_s_setprio(1);
#pragma unroll
      for (int fj = 0; fj < 4; ++fj) {
        acc[2 * q][fj] = __builtin_amdgcn_mfma_f32_16x16x32_bf16(a0, bfv[fj], acc[2 * q][fj], 0, 0, 0);
        acc[2 * q + 1][fj] = __builtin_amdgcn_mfma_f32_16x16x32_bf16(a1, bfv[fj], acc[2 * q + 1][fj], 0, 0, 0);
      }
      __builtin_amdgcn_s_setprio(0);
    }
    __syncthreads();
  }
#pragma unroll
  for (int fi = 0; fi < 8; ++fi)
#pragma unroll
    for (int fj = 0; fj < 4; ++fj) {
      size_t col = bn + wc * 64 + fj * 16 + fr;
#pragma unroll
      for (int e = 0; e < 4; ++e) {
        size_t r = bm + wr * 128 + fi * 16 + j4 * 4 + e;
        size_t off = r * ldC + col;
        if (BF16OUT) reinterpret_cast<us*>(Cout)[off] = f2b(acc[fi][fj][e]);
        else reinterpret_cast<float*>(Cout)[off] = acc[fi][fj][e];
      }
    }
}

// ---------------- 128^2 GEMM (kept for the tiny ba projection) ----------------
__global__ __launch_bounds__(256) void gemm_lds_f32(const us* __restrict__ A,
    const us* __restrict__ B, float* __restrict__ Cout,
    int K, int Nb1, int Nvalid, int ldC) {
  __shared__ us Ash[128 * 64];
  __shared__ us Bsh[128 * 64];
  int tid = threadIdx.x, w = tid >> 6, lane = tid & 63;
  int bm = blockIdx.x * 128, bn = blockIdx.y * 128;
  int wm = (w >> 1) * 64, wn = (w & 1) * 64;
  const us* aP[4]; const us* bP[4]; us* lA[4]; us* lB[4];
#pragma unroll
  for (int i = 0; i < 4; ++i) {
    int idx = i * 256 + tid;
    int row = idx >> 3;
    int sg = ((idx & 7) ^ (row & 7)) * 8;
    aP[i] = A + (size_t)(bm + row) * K + sg;
    int rb = bn + row; if (rb > Nb1) rb = Nb1;
    bP[i] = B + (size_t)rb * K + sg;
    lA[i] = &Ash[(i * 256 + w * 64) * 8];
    lB[i] = &Bsh[(i * 256 + w * 64) * 8];
  }
  f32x4 acc[4][4] = {};
  int fr = lane & 15, j = lane >> 4;
  for (int kt = 0; kt < K; kt += 64) {
#pragma unroll
    for (int i = 0; i < 4; ++i)
      __builtin_amdgcn_global_load_lds((const void*)(aP[i] + kt), (void*)lA[i], 16, 0, 0);
#pragma unroll
    for (int i = 0; i < 4; ++i)
      __builtin_amdgcn_global_load_lds((const void*)(bP[i] + kt), (void*)lB[i], 16, 0, 0);
    __syncthreads();
#pragma unroll
    for (int ks = 0; ks < 2; ++ks) {
      short8 af[4], bfr[4];
#pragma unroll
      for (int f = 0; f < 4; ++f) {
        int Ra = wm + f * 16 + fr;
        af[f] = *reinterpret_cast<const short8*>(&Ash[Ra * 64 + (((ks * 4 + j) ^ (Ra & 7)) * 8)]);
        int Rb = wn + f * 16 + fr;
        bfr[f] = *reinterpret_cast<const short8*>(&Bsh[Rb * 64 + (((ks * 4 + j) ^ (Rb & 7)) * 8)]);
      }
#pragma unroll
      for (int i = 0; i < 4; ++i)
#pragma unroll
        for (int jj = 0; jj < 4; ++jj)
          acc[i][jj] = __builtin_amdgcn_mfma_f32_16x16x32_bf16(af[i], bfr[jj], acc[i][jj], 0, 0, 0);
    }
    __syncthreads();
  }
#pragma unroll
  for (int i = 0; i < 4; ++i)
#pragma unroll
    for (int jj = 0; jj < 4; ++jj) {
      int c0 = bn + wn + jj * 16 + (lane & 15);
      if (c0 < Nvalid) {
#pragma unroll
        for (int e = 0; e < 4; ++e) {
          int r = bm + wm + i * 16 + (lane >> 4) * 4 + e;
          Cout[(size_t)r * ldC + c0] = acc[i][jj][e];
        }
      }
    }
}

// -------- conv(KC=4)+silu (+l2norm), 4 tokens/block, 8 contiguous channels/thread --------
template <int MODE>
__global__ __launch_bounds__(256) void conv_chunk(const us* __restrict__ mixed,
    const float* __restrict__ cw, us* __restrict__ outp, int headbase) {
  int bp = blockIdx.x, b = bp >> 10, tloc = (bp & 1023) * 4, tid = threadIdx.x;
  int c0 = tid * 8;
  float wv[8][4];
#pragma unroll
  for (int jj = 0; jj < 8; ++jj) {
    float4 w4 = *reinterpret_cast<const float4*>(cw + (size_t)(c0 + jj) * 4);
    wv[jj][0] = w4.x; wv[jj][1] = w4.y; wv[jj][2] = w4.z; wv[jj][3] = w4.w;
  }
  // rows tloc-3 .. tloc+3 (7 rows) feed tokens {tloc .. tloc+3}
  us rw[7][8];
#pragma unroll
  for (int i = 0; i < 7; ++i) {
    int tt = tloc - 3 + i;
    if (tt >= 0 && tt < 4096)
      *reinterpret_cast<uint4*>(rw[i]) = *reinterpret_cast<const uint4*>(
          mixed + ((size_t)(b * 4096 + tt)) * 2048 + c0);
    else
      *reinterpret_cast<uint4*>(rw[i]) = make_uint4(0, 0, 0, 0);
  }
  float x[4][8];
#pragma unroll
  for (int jj = 0; jj < 8; ++jj) {
#pragma unroll
    for (int tk = 0; tk < 4; ++tk) {
      float a = 0.f;
#pragma unroll
      for (int i = 0; i < 4; ++i) a += b2f(rw[tk + i][jj]) * wv[jj][i];
      x[tk][jj] = a / (1.f + __expf(-a));
    }
  }
  size_t bt0 = (size_t)b * 4096 + tloc;
  us ov[8];
  if (MODE < 2) {
    float s[4] = {};
#pragma unroll
    for (int tk = 0; tk < 4; ++tk) {
#pragma unroll
      for (int jj = 0; jj < 8; ++jj) s[tk] += x[tk][jj] * x[tk][jj];
    }
#pragma unroll
    for (int m = 1; m < 16; m <<= 1) {
#pragma unroll
      for (int tk = 0; tk < 4; ++tk) s[tk] += __shfl_xor(s[tk], m, 64);
    }
    const float sc = (MODE == 0 ? 0.08838834764831845f : 1.f);
    int head = tid >> 4, d0 = c0 & 127;
#pragma unroll
    for (int tk = 0; tk < 4; ++tk) {
      float rn = rsqrtf(s[tk] + 1e-6f) * sc;
#pragma unroll
      for (int jj = 0; jj < 8; ++jj) ov[jj] = f2b(x[tk][jj] * rn);
      *reinterpret_cast<uint4*>(outp + ((bt0 + tk) * 16 + head) * 128 + d0) =
          *reinterpret_cast<uint4*>(ov);
    }
  } else {
    int head = headbase + (c0 >> 7), d0 = c0 & 127;
#pragma unroll
    for (int tk = 0; tk < 4; ++tk) {
#pragma unroll
      for (int jj = 0; jj < 8; ++jj) ov[jj] = f2b(x[tk][jj]);
      *reinterpret_cast<uint4*>(outp + ((bt0 + tk) * 32 + head) * 128 + d0) =
          *reinterpret_cast<uint4*>(ov);
    }
  }
}

// -------- gates: beta/g from ba, cumsum g within chunks of 64 --------
__global__ __launch_bounds__(256) void gates_cumsum(const float* __restrict__ ba,
    const float* __restrict__ dt_bias, const float* __restrict__ A_log,
    float* __restrict__ bl_g, float* __restrict__ beta_g) {
  int widx = blockIdx.x * 4 + (threadIdx.x >> 6);
  int lane = threadIdx.x & 63;
  int bh = widx >> 6, chunk = widx & 63;
  int b = bh >> 5, h = bh & 31;
  size_t btl = (size_t)b * 4096 + chunk * 64 + lane;
  float bv = ba[btl * 64 + h];
  float av = ba[btl * 64 + 32 + h];
  float beta = 1.f / (1.f + __expf(-bv));
  float xx = av + dt_bias[h];
  float sp = (xx > 20.f) ? xx : log1pf(__expf(xx));
  float g = -__expf(A_log[h]) * sp;
#pragma unroll
  for (int off = 1; off < 64; off <<= 1) {
    float n = __shfl_up(g, off, 64);
    if (lane >= off) g += n;
  }
  bl_g[(size_t)widx * 64 + lane] = g;
  beta_g[(size_t)widx * 64 + lane] = beta;
}

// ---------------- MFMA tile helpers ----------------
static __device__ __forceinline__ f32x4 tile_range(const us* A, int lda,
    const us* B, int ldb, int rt, int ct, int l0, int nk, int lane, f32x4 acc) {
  const us* ar = A + (rt * 16 + (lane & 15)) * lda + l0 * 16 + (lane >> 4) * 8;
  const us* br = B + (ct * 16 + (lane & 15)) * ldb + l0 * 16 + (lane >> 4) * 8;
#pragma unroll
  for (int ks = 0; ks < nk; ++ks) {
    short8 a = *reinterpret_cast<const short8*>(ar + ks * 32);
    short8 bb = *reinterpret_cast<const short8*>(br + ks * 32);
    acc = __builtin_amdgcn_mfma_f32_16x16x32_bf16(a, bb, acc, 0, 0, 0);
  }
  return acc;
}
// swizzled variant: slot' = slot ^ ((row >> SA/SB) & 7); SA/SB < 0 => no swizzle
template <int SA, int SB>
static __device__ __forceinline__ f32x4 tile_swz(const us* A, int lda,
    const us* B, int ldb, int rt, int ct, int nk, int lane, f32x4 acc) {
  int ra = rt * 16 + (lane & 15);
  int rb = ct * 16 + (lane & 15);
  int j = lane >> 4;
#pragma unroll
  for (int ks = 0; ks < nk; ++ks) {
    int slot = j + 4 * ks;
    int oa = (SA >= 0) ? ((slot ^ ((ra >> SA) & 7)) * 8) : (slot * 8);
    int ob = (SB >= 0) ? ((slot ^ ((rb >> SB) & 7)) * 8) : (slot * 8);
    short8 a = *reinterpret_cast<const short8*>(A + ra * lda + oa);
    short8 bb = *reinterpret_cast<const short8*>(B + rb * ldb + ob);
    acc = __builtin_amdgcn_mfma_f32_16x16x32_bf16(a, bb, acc, 0, 0, 0);
  }
  return acc;
}

// =======================================================================
// Scan pass 1 (chunk-parallel): per (bh, chunk) compute T=(I+D)^-1 -> Tg.
// =======================================================================
__global__ __launch_bounds__(512, 1) void scan_p1(
    const us* __restrict__ k, const float* __restrict__ bl_g,
    const float* __restrict__ beta_g, us* __restrict__ Tg) {
  __shared__ us Kb[64 * 136];
  __shared__ us Ebt[64 * 72];
  __shared__ us W1[64 * 72], W1t[64 * 72], W3[64 * 72];
  __shared__ float bl_s[64], bet_s[64];
  us* const Eb = Kb;

  int bid = blockIdx.x, bh = bid >> 6, c = bid & 63;
  int b = bh >> 5, h = bh & 31, hk = h >> 1;
  int tid = threadIdx.x, w = tid >> 6, lane = tid & 63;
  int row = tid >> 3, c16 = (tid & 7) * 16;
  size_t bt0 = (size_t)b * 4096 + c * 64;

  const int TR_[10] = {0, 1, 1, 2, 2, 2, 3, 3, 3, 3};
  const int TC_[10] = {0, 0, 1, 0, 1, 2, 0, 1, 2, 3};

  const us* kp = k + ((bt0 + row) * 16 + hk) * 128 + c16;
  uint4 kr0 = reinterpret_cast<const uint4*>(kp)[0];
  uint4 kr1 = reinterpret_cast<const uint4*>(kp)[1];
  int gbase = (bh * 64 + c) * 64;
  if (tid < 64) { bl_s[tid] = bl_g[gbase + tid]; bet_s[tid] = beta_g[gbase + tid]; }
  *reinterpret_cast<uint4*>(&Kb[row * 136 + c16]) = kr0;
  *reinterpret_cast<uint4*>(&Kb[row * 136 + c16 + 8]) = kr1;
  __syncthreads();
  {
    int art = w & 3;
#pragma unroll
    for (int s = 0; s < 2; ++s) {
      int ct = (w >> 2) * 2 + s;
      f32x4 a = tile_range(Kb, 136, Kb, 136, art, ct, 0, 4, lane, f32x4{});
#pragma unroll
      for (int e = 0; e < 4; ++e) {
        int tr = art * 16 + (lane >> 4) * 4 + e;
        int cl = ct * 16 + (lane & 15);
        float dv = (cl < tr) ? bet_s[tr] * __expf(bl_s[tr] - bl_s[cl]) * a[e] : 0.f;
        W1[tr * 72 + cl] = f2b(dv);
        W1t[cl * 72 + tr] = f2b(dv);
        W3[tr * 72 + cl] = f2b((tr == cl ? 1.f : 0.f) - dv);
      }
    }
  }
  __syncthreads();
  f32x4 freg[2] = {};
#pragma unroll
  for (int it = 1; it <= 5; ++it) {
    if (it > 1) {
#pragma unroll
      for (int s = 0; s < 2; ++s) {
        int j = w + s * 8;
        if (j < 10) {
          int r = TR_[j], cc0 = TC_[j];
#pragma unroll
          for (int e = 0; e < 4; ++e) {
            int rr = r * 16 + (lane >> 4) * 4 + e, cl = cc0 * 16 + (lane & 15);
            W3[rr * 72 + cl] = f2b(b2f(W3[rr * 72 + cl]) + freg[s][e]);
          }
        }
      }
    }
    if (it == 1) {
      const int ZR[12] = {0, 0, 0, 1, 1, 2, 1, 2, 2, 3, 3, 3};
      const int ZC[12] = {1, 2, 3, 2, 3, 3, 0, 0, 1, 0, 1, 2};
#pragma unroll
      for (int u = 0; u < 12; ++u) {
        if ((u & 7) != w) continue;
        us* arr = (u < 6) ? Eb : Ebt;
        if (lane < 32) {
          int rr = ZR[u] * 16 + (lane >> 1);
          *reinterpret_cast<uint4*>(&arr[rr * 72 + ZC[u] * 16 + (lane & 1) * 8]) =
              make_uint4(0, 0, 0, 0);
        }
      }
    }
    const us* Es  = (it & 1) ? W1  : Eb;
    const us* Est = (it & 1) ? W1t : Ebt;
    us* Ed  = (it & 1) ? Eb  : W1;
    us* Edt = (it & 1) ? Ebt : W1t;
#pragma unroll
    for (int s = 0; s < 2; ++s) {
      int j = w + s * 8;
      if (j < 10) {
        int r = TR_[j], cc0 = TC_[j];
        int l0 = cc0 & ~1, nk = (r - l0 + 2) >> 1;
        f32x4 a = tile_range(Es, 72, Est, 72, r, cc0, l0, nk, lane, f32x4{});
#pragma unroll
        for (int e = 0; e < 4; ++e) {
          int rr = r * 16 + (lane >> 4) * 4 + e, cl = cc0 * 16 + (lane & 15);
          us val = f2b(a[e]);
          Ed[rr * 72 + cl] = val;
          Edt[cl * 72 + rr] = val;
        }
      }
    }
    __syncthreads();
    const us* Ent = (it & 1) ? Ebt : W1t;
#pragma unroll
    for (int s = 0; s < 2; ++s) {
      int j = w + s * 8;
      if (j < 10) {
        int r = TR_[j], cc0 = TC_[j];
        int l0 = cc0 & ~1, nk = (r - l0 + 2) >> 1;
        freg[s] = tile_range(W3, 72, Ent, 72, r, cc0, l0, nk, lane, f32x4{});
      }
    }
    __syncthreads();
  }
#pragma unroll
  for (int s = 0; s < 2; ++s) {
    int j = w + s * 8;
    if (j < 10) {
      int r = TR_[j], cc0 = TC_[j];
#pragma unroll
      for (int e = 0; e < 4; ++e) {
        int rr = r * 16 + (lane >> 4) * 4 + e, cl = cc0 * 16 + (lane & 15);
        W3[rr * 72 + cl] = f2b(b2f(W3[rr * 72 + cl]) + freg[s][e]);
      }
    }
  }
  __syncthreads();
  *reinterpret_cast<uint4*>(&Tg[(size_t)bid * 4096 + tid * 8]) =
      *reinterpret_cast<const uint4*>(&W3[row * 72 + (tid & 7) * 8]);
}

// =======================================================================
// Scan pass 2: sequential over chunks, 4x V-split (256 blocks).
// Swizzled Vt/Ut (slot ^ v>>3) + vectorized Ktb transpose (slot ^ d>>4).
// =======================================================================
__global__ __launch_bounds__(512, 1) void scan_p2(
    const us* __restrict__ q, const us* __restrict__ k, const us* __restrict__ v,
    const float* __restrict__ bl_g, const float* __restrict__ beta_g,
    const us* __restrict__ Tg, us* __restrict__ o) {
  __shared__ us Sb[32 * 136];
  __shared__ us Kb[64 * 136];
  __shared__ us Qb[64 * 136];
  __shared__ us Ktb[128 * 72];   // e^{bC-b_t} K^T [d][t], slot ^ (d>>4)
  __shared__ us Vt[32 * 72];     // [v][t], slot ^ (v>>3)
  __shared__ us Ut[32 * 72];     // [v][t], slot ^ (v>>3)
  __shared__ us W3[64 * 72];
  __shared__ us WP[64 * 72];
  __shared__ float bl_s[64], bet_s[64], ksc_s[64];

  int bid = blockIdx.x, vs = bid >> 6, bh = bid & 63;
  int b = bh >> 5, h = bh & 31, hk = h >> 1;
  int tid = threadIdx.x, w = tid >> 6, lane = tid & 63;
  int row = tid >> 3, c16 = (tid & 7) * 16;

  for (int i = tid; i < (32 * 136) / 8; i += 512)
    reinterpret_cast<uint4*>(Sb)[i] = make_uint4(0, 0, 0, 0);
  __syncthreads();

  uint4 kr0, kr1, qr0, qr1, vr, Tr;
  float blr, blC, bet, betv;
  int vrow = (tid & 255) >> 2, vseg = tid & 3;
  auto load_regs = [&](int c) {
    size_t bt0 = (size_t)b * 4096 + c * 64;
    const us* kp = k + ((bt0 + row) * 16 + hk) * 128 + c16;
    const us* qp = q + ((bt0 + row) * 16 + hk) * 128 + c16;
    kr0 = reinterpret_cast<const uint4*>(kp)[0];
    kr1 = reinterpret_cast<const uint4*>(kp)[1];
    qr0 = reinterpret_cast<const uint4*>(qp)[0];
    qr1 = reinterpret_cast<const uint4*>(qp)[1];
    Tr = *reinterpret_cast<const uint4*>(&Tg[((size_t)bh * 64 + c) * 4096 + tid * 8]);
    int gbase = (bh * 64 + c) * 64;
    blr = bl_g[gbase + row];
    blC = bl_g[gbase + 63];
    bet = beta_g[gbase + row];
    if (tid < 256) {
      vr = *reinterpret_cast<const uint4*>(
          v + ((bt0 + vrow) * 32 + h) * 128 + vs * 32 + vseg * 8);
      betv = beta_g[gbase + vrow];
    }
  };
  load_regs(0);

  for (int c = 0; c < 64; ++c) {
    size_t bt0 = (size_t)b * 4096 + c * 64;
    // ---- LF ----
    if ((tid & 7) == 0) {
      bl_s[row] = blr; bet_s[row] = bet;
      ksc_s[row] = __expf(blC - blr);
    }
    *reinterpret_cast<uint4*>(&Kb[row * 136 + c16]) = kr0;
    *reinterpret_cast<uint4*>(&Kb[row * 136 + c16 + 8]) = kr1;
    *reinterpret_cast<uint4*>(&Qb[row * 136 + c16]) = qr0;
    *reinterpret_cast<uint4*>(&Qb[row * 136 + c16 + 8]) = qr1;
    *reinterpret_cast<uint4*>(&W3[row * 72 + (tid & 7) * 8]) = Tr;
    if (tid < 256) {
      us vreg[8];
      *reinterpret_cast<uint4*>(vreg) = vr;
#pragma unroll
      for (int i = 0; i < 8; ++i) {
        int vv = vseg * 8 + i;
        Vt[vv * 72 + (((vrow >> 3) ^ vseg) & 7) * 8 + (vrow & 7)] = f2b(betv * b2f(vreg[i]));
      }
    }
    load_regs(c < 63 ? c + 1 : 63);
    bar_lds();
    // ---- G1: Ktb build + Q.S0 + P + RHS ----
#pragma unroll
    for (int tk = 0; tk < 2; ++tk) {
      int task = tid + tk * 512;
      int d = task & 127, oct = task >> 7;
      us kt[8];
#pragma unroll
      for (int i = 0; i < 8; ++i)
        kt[i] = f2b(ksc_s[oct * 8 + i] * b2f(Kb[(oct * 8 + i) * 136 + d]));
      *reinterpret_cast<uint4*>(&Ktb[d * 72 + ((oct ^ ((d >> 4) & 7)) * 8)]) =
          *reinterpret_cast<uint4*>(kt);
    }
    int rtO = w >> 1, ctv = w & 1;
    f32x4 o1 = tile_swz<-1, -1>(Qb, 136, Sb, 136, rtO, ctv, 4, lane, f32x4{});
    {
      int art = w & 3;
#pragma unroll
      for (int s = 0; s < 2; ++s) {
        int ct = (w >> 2) * 2 + s;
        f32x4 a = tile_swz<-1, -1>(Qb, 136, Kb, 136, art, ct, 4, lane, f32x4{});
#pragma unroll
        for (int e = 0; e < 4; ++e) {
          int tr = art * 16 + (lane >> 4) * 4 + e;
          int cl = ct * 16 + (lane & 15);
          float pv = (cl <= tr) ? __expf(bl_s[tr] - bl_s[cl]) * a[e] : 0.f;
          WP[tr * 72 + cl] = f2b(pv);
        }
      }
    }
    {
      int vrt = w >> 2, ct = w & 3;
      f32x4 a = tile_swz<-1, -1>(Sb, 136, Kb, 136, vrt, ct, 4, lane, f32x4{});
      int tt = ct * 16 + (lane & 15);
      float csc = bet_s[tt] * __expf(bl_s[tt]);
#pragma unroll
      for (int e = 0; e < 4; ++e) {
        int vv = vrt * 16 + (lane >> 4) * 4 + e;
        int off = vv * 72 + (((tt >> 3) ^ ((vv >> 3) & 7)) * 8) + (tt & 7);
        Vt[off] = f2b(b2f(Vt[off]) - csc * a[e]);
      }
    }
    bar_lds();
    // ---- G2: Ut = RHS^T . T^T ----
    {
      int vrt = w >> 2, ct = w & 3;
      f32x4 a = tile_swz<3, -1>(Vt, 72, W3, 72, vrt, ct, 2, lane, f32x4{});
#pragma unroll
      for (int e = 0; e < 4; ++e) {
        int uv = vrt * 16 + (lane >> 4) * 4 + e;
        int ut2 = ct * 16 + (lane & 15);
        Ut[uv * 72 + (((ut2 >> 3) ^ ((uv >> 3) & 7)) * 8) + (ut2 & 7)] = f2b(a[e]);
      }
    }
    bar_lds();
    // ---- OS: O write + S update ----
    float lamC = __expf(bl_s[63]);
    {
      f32x4 a = tile_swz<-1, 3>(WP, 72, Ut, 72, rtO, ctv, 2, lane, f32x4{});
#pragma unroll
      for (int e = 0; e < 4; ++e) {
        int tt = rtO * 16 + (lane >> 4) * 4 + e;
        int vv = vs * 32 + ctv * 16 + (lane & 15);
        float val = __expf(bl_s[tt]) * o1[e] + a[e];
        o[((bt0 + tt) * 32 + h) * 128 + vv] = f2b(val);
      }
    }
#pragma unroll
    for (int s = 0; s < 2; ++s) {
      int ti = w * 2 + s;
      int vrt = ti >> 3, dt = ti & 7;
      f32x4 a = tile_swz<3, 4>(Ut, 72, Ktb, 72, vrt, dt, 2, lane, f32x4{});
#pragma unroll
      for (int e = 0; e < 4; ++e) {
        int vv = vrt * 16 + (lane >> 4) * 4 + e, dd = dt * 16 + (lane & 15);
        Sb[vv * 136 + dd] = f2b(lamC * b2f(Sb[vv * 136 + dd]) + a[e]);
      }
    }
    bar_lds();
  }
}

// ---------------- gated RMSNorm, in place, vectorized ----------------
__global__ __launch_bounds__(256) void rms_gate(us* oy,
    const us* __restrict__ z, const float* __restrict__ nw) {
  int sub = threadIdx.x & 31;
  size_t row = (size_t)blockIdx.x * 8 + (threadIdx.x >> 5);
  size_t base = row * 128 + sub * 4;
  ushort4 ov = *reinterpret_cast<ushort4*>(oy + base);
  ushort4 zv = *reinterpret_cast<const ushort4*>(z + base);
  float o_[4] = {b2f(ov.x), b2f(ov.y), b2f(ov.z), b2f(ov.w)};
  float ss = o_[0] * o_[0] + o_[1] * o_[1] + o_[2] * o_[2] + o_[3] * o_[3];
#pragma unroll
  for (int m = 1; m < 32; m <<= 1) ss += __shfl_xor(ss, m, 64);
  float r = rsqrtf(ss * (1.f / 128.f) + 1e-6f);
  float4 w4 = *reinterpret_cast<const float4*>(nw + sub * 4);
  float zz[4] = {b2f(zv.x), b2f(zv.y), b2f(zv.z), b2f(zv.w)};
  float wv[4] = {w4.x, w4.y, w4.z, w4.w};
  us res[4];
#pragma unroll
  for (int i = 0; i < 4; ++i) {
    float zs = zz[i] / (1.f + __expf(-zz[i]));
    res[i] = f2b(o_[i] * r * wv[i] * zs);
  }
  *reinterpret_cast<ushort4*>(oy + base) = *reinterpret_cast<ushort4*>(res);
}

extern "C" void kernel_launch(void* const* d_in, const int* in_sizes, int n_in,
                              void* d_out, int out_size, void* d_ws, size_t ws_size,
                              hipStream_t stream) {
  const float* hs      = (const float*)d_in[0];
  const float* W_qkv   = (const float*)d_in[1];
  const float* W_z     = (const float*)d_in[2];
  const float* W_b     = (const float*)d_in[3];
  const float* W_a     = (const float*)d_in[4];
  const float* conv_w  = (const float*)d_in[5];
  const float* dt_bias = (const float*)d_in[6];
  const float* A_log   = (const float*)d_in[7];
  const float* norm_w  = (const float*)d_in[8];
  const float* W_out   = (const float*)d_in[9];
  float* out = (float*)d_out;

  char* ws = (char*)d_ws;
  const size_t MiB = 1u << 20;
  float* ba_buf = (float*)(ws);
  float* bl_g   = (float*)(ws + 2 * MiB);
  float* bt_g   = (float*)(ws + 3 * MiB);
  us*    wt     = (us*)(ws + 4 * MiB);
  us*    Tg     = (us*)(ws + 4 * MiB);
  us*    mixed  = (us*)(ws + 36 * MiB);
  us*    o_buf  = (us*)(ws + 36 * MiB);
  us*    hs_bf0 = (us*)(ws + 68 * MiB);
  us*    q_buf  = (us*)(ws + 100 * MiB);
  us*    hs_bf1 = q_buf;
  us*    k_buf  = (us*)(ws + 132 * MiB);
  us*    v_buf  = (us*)(ws + 164 * MiB);
  us*    z_bf   = v_buf;

  cvt_f32_bf16<<<2048, 256, 0, stream>>>(hs, hs_bf0, (long)8192 * 2048 / 4);

  for (int c = 0; c < 4; ++c) {
    transpose_cvt<<<dim3(32, 32), 256, 0, stream>>>(W_qkv, wt, 2048, 2048, 8192, c * 2048, 0);
    gemm256<true><<<dim3(32, 8), 512, 0, stream>>>(hs_bf0, wt, mixed, 2048, 2048);
    const float* cwc = conv_w + (size_t)c * 2048 * 4;
    if (c == 0)      conv_chunk<0><<<2048, 256, 0, stream>>>(mixed, cwc, q_buf, 0);
    else if (c == 1) conv_chunk<1><<<2048, 256, 0, stream>>>(mixed, cwc, k_buf, 0);
    else if (c == 2) conv_chunk<2><<<2048, 256, 0, stream>>>(mixed, cwc, v_buf, 0);
    else             conv_chunk<2><<<2048, 256, 0, stream>>>(mixed, cwc, v_buf, 16);
  }
  transpose_cvt<<<dim3(1, 32), 256, 0, stream>>>(W_b, wt, 2048, 32, 32, 0, 0);
  transpose_cvt<<<dim3(1, 32), 256, 0, stream>>>(W_a, wt, 2048, 32, 32, 0, 32);
  gemm_lds_f32<<<dim3(64, 1), 256, 0, stream>>>(hs_bf0, wt, ba_buf, 2048, 63, 64, 64);
  gates_cumsum<<<1024, 256, 0, stream>>>(ba_buf, dt_bias, A_log, bl_g, bt_g);
  scan_p1<<<4096, 512, 0, stream>>>(k_buf, bl_g, bt_g, Tg);
  scan_p2<<<256, 512, 0, stream>>>(q_buf, k_buf, v_buf, bl_g, bt_g, Tg, o_buf);
  cvt_f32_bf16<<<2048, 256, 0, stream>>>(hs, hs_bf1, (long)8192 * 2048 / 4);
  transpose_cvt<<<dim3(64, 32), 256, 0, stream>>>(W_z, wt, 2048, 4096, 4096, 0, 0);
  gemm256<true><<<dim3(32, 16), 512, 0, stream>>>(hs_bf1, wt, z_bf, 2048, 4096);
  rms_gate<<<32768, 256, 0, stream>>>(o_buf, z_bf, norm_w);
  transpose_cvt<<<dim3(32, 64), 256, 0, stream>>>(W_out, wt, 4096, 2048, 2048, 0, 0);
  gemm256<false><<<dim3(32, 8), 512, 0, stream>>>(o_buf, wt, out, 4096, 2048);
}

// Round 18
// 1054.622 us; speedup vs baseline: 1.1716x; 1.1716x over previous
//
#include <hip/hip_runtime.h>
#include <hip/hip_bf16.h>

// Qwen3.5 GatedDeltaNet: B=2, T=4096, D=2048, NV=32, NK=16, DK=DV=128, KC=4
// Round 18: round-15 source (proven 1081us: gemm256 BK=64 drain schedule,
// swizzled scan) + round-16's conv_chunk 4-tokens/block (compile-proven).
// Round 17 was a transcription error (malformed tile_swz call), not a result.

typedef __attribute__((ext_vector_type(8))) short short8;
typedef __attribute__((ext_vector_type(4))) float f32x4;
typedef unsigned short us;

static __device__ __forceinline__ us f2b(float f) {
  __hip_bfloat16 h = __float2bfloat16(f);
  return __builtin_bit_cast(us, h);
}
static __device__ __forceinline__ float b2f(us u) {
  return __bfloat162float(__builtin_bit_cast(__hip_bfloat16, u));
}
// barrier that publishes LDS (lgkmcnt) but leaves global loads/stores in flight
static __device__ __forceinline__ void bar_lds() {
  asm volatile("s_waitcnt lgkmcnt(0)" ::: "memory");
  __builtin_amdgcn_s_barrier();
}

// ---------------- fp32 -> bf16 elementwise ----------------
__global__ __launch_bounds__(256) void cvt_f32_bf16(const float* __restrict__ in,
    us* __restrict__ out, long n4) {
  long i = (long)blockIdx.x * 256 + threadIdx.x;
  long stride = (long)gridDim.x * 256;
  for (; i < n4; i += stride) {
    float4 f = reinterpret_cast<const float4*>(in)[i];
    ushort4 u;
    u.x = f2b(f.x); u.y = f2b(f.y); u.z = f2b(f.z); u.w = f2b(f.w);
    reinterpret_cast<ushort4*>(out)[i] = u;
  }
}

// ------- fp32 [K][Nfull] (col slice) -> bf16 [N][K] transpose, 64x64 tiles -------
__global__ __launch_bounds__(256) void transpose_cvt(const float* __restrict__ in,
    us* __restrict__ out, int K, int N, int Nfull, int coloff, int row_off) {
  __shared__ float tile[64][65];
  int tid = threadIdx.x;
  int n0 = blockIdx.x * 64, k0 = blockIdx.y * 64;
  int tx = tid & 15, ty = tid >> 4;
#pragma unroll
  for (int r = 0; r < 4; ++r) {
    int kk = k0 + ty + r * 16, nn = n0 + tx * 4;
    float4 v = make_float4(0.f, 0.f, 0.f, 0.f);
    if (kk < K && nn < N)
      v = *reinterpret_cast<const float4*>(in + (size_t)kk * Nfull + coloff + nn);
    tile[ty + r * 16][tx * 4 + 0] = v.x;
    tile[ty + r * 16][tx * 4 + 1] = v.y;
    tile[ty + r * 16][tx * 4 + 2] = v.z;
    tile[ty + r * 16][tx * 4 + 3] = v.w;
  }
  __syncthreads();
#pragma unroll
  for (int g = 0; g < 2; ++g) {
    int s = tid + g * 256;
    int nn = s >> 3, ks = (s & 7) * 8;
    if (n0 + nn < N && k0 + ks < K) {
      us ov[8];
#pragma unroll
      for (int i = 0; i < 8; ++i) ov[i] = f2b(tile[ks + i][nn]);
      *reinterpret_cast<uint4*>(out + (size_t)(n0 + nn + row_off) * K + k0 + ks) =
          *reinterpret_cast<uint4*>(ov);
    }
  }
}

// ================= 256x256 8-wave double-buffered TN GEMM (round-8) =================
template <bool BF16OUT>
__global__ __launch_bounds__(512, 1) void gemm256(const us* __restrict__ A,
    const us* __restrict__ B, void* __restrict__ Cout, int K, int ldC) {
  __shared__ us Abuf[2][256 * 64];
  __shared__ us Bbuf[2][256 * 64];
  int tid = threadIdx.x, w = tid >> 6, lane = tid & 63;
  int wr = w >> 2, wc = w & 3;
  int fr = lane & 15, j4 = lane >> 4;
  int lin = blockIdx.y * gridDim.x + blockIdx.x;
  int nwg = gridDim.x * gridDim.y;
  int wg = (lin & 7) * (nwg >> 3) + (lin >> 3);
  int bx = wg % gridDim.x, by = wg / gridDim.x;
  size_t bm = (size_t)bx * 256, bn = (size_t)by * 256;

  const us *aG[4], *bG[4];
  us *aL[2][4], *bL[2][4];
#pragma unroll
  for (int u = 0; u < 4; ++u) {
    int idx = u * 512 + tid;
    int row = idx >> 3, sl = idx & 7;
    int sg = (sl ^ (row & 7)) * 8;
    aG[u] = A + (bm + row) * K + sg;
    bG[u] = B + (bn + row) * K + sg;
    int lbase = (u * 64 + w * 8) * 64;
#pragma unroll
    for (int bf = 0; bf < 2; ++bf) {
      aL[bf][u] = &Abuf[bf][lbase];
      bL[bf][u] = &Bbuf[bf][lbase];
    }
  }

  f32x4 acc[8][4] = {};
#pragma unroll
  for (int u = 0; u < 4; ++u) {
    __builtin_amdgcn_global_load_lds((const void*)aG[u], (void*)aL[0][u], 16, 0, 0);
    __builtin_amdgcn_global_load_lds((const void*)bG[u], (void*)bL[0][u], 16, 0, 0);
  }
  __syncthreads();

  int nt = K >> 6;
  for (int t = 0; t < nt; ++t) {
    int cur = t & 1, nxt = cur ^ 1;
    const us* Ac = Abuf[cur];
    const us* Bc = Bbuf[cur];
    int kt1 = (t + 1) << 6;
    bool more = (t + 1 < nt);
#pragma unroll
    for (int q = 0; q < 4; ++q) {
      if (more) {
        __builtin_amdgcn_global_load_lds((const void*)(aG[q] + kt1), (void*)aL[nxt][q], 16, 0, 0);
        __builtin_amdgcn_global_load_lds((const void*)(bG[q] + kt1), (void*)bL[nxt][q], 16, 0, 0);
      }
      short8 a0[2], a1[2], bfv[4][2];
      int Ra0 = wr * 128 + 2 * q * 16 + fr;
      int Ra1 = Ra0 + 16;
#pragma unroll
      for (int ks = 0; ks < 2; ++ks) {
        a0[ks] = *reinterpret_cast<const short8*>(&Ac[Ra0 * 64 + (((ks * 4 + j4) ^ (Ra0 & 7)) * 8)]);
        a1[ks] = *reinterpret_cast<const short8*>(&Ac[Ra1 * 64 + (((ks * 4 + j4) ^ (Ra1 & 7)) * 8)]);
#pragma unroll
        for (int fj = 0; fj < 4; ++fj) {
          int Rb = wc * 64 + fj * 16 + fr;
          bfv[fj][ks] = *reinterpret_cast<const short8*>(&Bc[Rb * 64 + (((ks * 4 + j4) ^ (Rb & 7)) * 8)]);
        }
      }
      __builtin_amdgcn_s_setprio(1);
#pragma unroll
      for (int ks = 0; ks < 2; ++ks)
#pragma unroll
        for (int fj = 0; fj < 4; ++fj) {
          acc[2 * q][fj] = __builtin_amdgcn_mfma_f32_16x16x32_bf16(a0[ks], bfv[fj][ks], acc[2 * q][fj], 0, 0, 0);
          acc[2 * q + 1][fj] = __builtin_amdgcn_mfma_f32_16x16x32_bf16(a1[ks], bfv[fj][ks], acc[2 * q + 1][fj], 0, 0, 0);
        }
      __builtin_amdgcn_s_setprio(0);
    }
    __syncthreads();
  }
#pragma unroll
  for (int fi = 0; fi < 8; ++fi)
#pragma unroll
    for (int fj = 0; fj < 4; ++fj) {
      size_t col = bn + wc * 64 + fj * 16 + fr;
#pragma unroll
      for (int e = 0; e < 4; ++e) {
        size_t r = bm + wr * 128 + fi * 16 + j4 * 4 + e;
        size_t off = r * ldC + col;
        if (BF16OUT) reinterpret_cast<us*>(Cout)[off] = f2b(acc[fi][fj][e]);
        else reinterpret_cast<float*>(Cout)[off] = acc[fi][fj][e];
      }
    }
}

// ---------------- 128^2 GEMM (kept for the tiny ba projection) ----------------
__global__ __launch_bounds__(256) void gemm_lds_f32(const us* __restrict__ A,
    const us* __restrict__ B, float* __restrict__ Cout,
    int K, int Nb1, int Nvalid, int ldC) {
  __shared__ us Ash[128 * 64];
  __shared__ us Bsh[128 * 64];
  int tid = threadIdx.x, w = tid >> 6, lane = tid & 63;
  int bm = blockIdx.x * 128, bn = blockIdx.y * 128;
  int wm = (w >> 1) * 64, wn = (w & 1) * 64;
  const us* aP[4]; const us* bP[4]; us* lA[4]; us* lB[4];
#pragma unroll
  for (int i = 0; i < 4; ++i) {
    int idx = i * 256 + tid;
    int row = idx >> 3;
    int sg = ((idx & 7) ^ (row & 7)) * 8;
    aP[i] = A + (size_t)(bm + row) * K + sg;
    int rb = bn + row; if (rb > Nb1) rb = Nb1;
    bP[i] = B + (size_t)rb * K + sg;
    lA[i] = &Ash[(i * 256 + w * 64) * 8];
    lB[i] = &Bsh[(i * 256 + w * 64) * 8];
  }
  f32x4 acc[4][4] = {};
  int fr = lane & 15, j = lane >> 4;
  for (int kt = 0; kt < K; kt += 64) {
#pragma unroll
    for (int i = 0; i < 4; ++i)
      __builtin_amdgcn_global_load_lds((const void*)(aP[i] + kt), (void*)lA[i], 16, 0, 0);
#pragma unroll
    for (int i = 0; i < 4; ++i)
      __builtin_amdgcn_global_load_lds((const void*)(bP[i] + kt), (void*)lB[i], 16, 0, 0);
    __syncthreads();
#pragma unroll
    for (int ks = 0; ks < 2; ++ks) {
      short8 af[4], bfr[4];
#pragma unroll
      for (int f = 0; f < 4; ++f) {
        int Ra = wm + f * 16 + fr;
        af[f] = *reinterpret_cast<const short8*>(&Ash[Ra * 64 + (((ks * 4 + j) ^ (Ra & 7)) * 8)]);
        int Rb = wn + f * 16 + fr;
        bfr[f] = *reinterpret_cast<const short8*>(&Bsh[Rb * 64 + (((ks * 4 + j) ^ (Rb & 7)) * 8)]);
      }
#pragma unroll
      for (int i = 0; i < 4; ++i)
#pragma unroll
        for (int jj = 0; jj < 4; ++jj)
          acc[i][jj] = __builtin_amdgcn_mfma_f32_16x16x32_bf16(af[i], bfr[jj], acc[i][jj], 0, 0, 0);
    }
    __syncthreads();
  }
#pragma unroll
  for (int i = 0; i < 4; ++i)
#pragma unroll
    for (int jj = 0; jj < 4; ++jj) {
      int c0 = bn + wn + jj * 16 + (lane & 15);
      if (c0 < Nvalid) {
#pragma unroll
        for (int e = 0; e < 4; ++e) {
          int r = bm + wm + i * 16 + (lane >> 4) * 4 + e;
          Cout[(size_t)r * ldC + c0] = acc[i][jj][e];
        }
      }
    }
}

// -------- conv(KC=4)+silu (+l2norm), 4 tokens/block, 8 contiguous channels/thread --------
template <int MODE>
__global__ __launch_bounds__(256) void conv_chunk(const us* __restrict__ mixed,
    const float* __restrict__ cw, us* __restrict__ outp, int headbase) {
  int bp = blockIdx.x, b = bp >> 10, tloc = (bp & 1023) * 4, tid = threadIdx.x;
  int c0 = tid * 8;
  float wv[8][4];
#pragma unroll
  for (int jj = 0; jj < 8; ++jj) {
    float4 w4 = *reinterpret_cast<const float4*>(cw + (size_t)(c0 + jj) * 4);
    wv[jj][0] = w4.x; wv[jj][1] = w4.y; wv[jj][2] = w4.z; wv[jj][3] = w4.w;
  }
  us rw[7][8];
#pragma unroll
  for (int i = 0; i < 7; ++i) {
    int tt = tloc - 3 + i;
    if (tt >= 0 && tt < 4096)
      *reinterpret_cast<uint4*>(rw[i]) = *reinterpret_cast<const uint4*>(
          mixed + ((size_t)(b * 4096 + tt)) * 2048 + c0);
    else
      *reinterpret_cast<uint4*>(rw[i]) = make_uint4(0, 0, 0, 0);
  }
  float x[4][8];
#pragma unroll
  for (int jj = 0; jj < 8; ++jj) {
#pragma unroll
    for (int tk = 0; tk < 4; ++tk) {
      float a = 0.f;
#pragma unroll
      for (int i = 0; i < 4; ++i) a += b2f(rw[tk + i][jj]) * wv[jj][i];
      x[tk][jj] = a / (1.f + __expf(-a));
    }
  }
  size_t bt0 = (size_t)b * 4096 + tloc;
  us ov[8];
  if (MODE < 2) {
    float s[4] = {};
#pragma unroll
    for (int tk = 0; tk < 4; ++tk) {
#pragma unroll
      for (int jj = 0; jj < 8; ++jj) s[tk] += x[tk][jj] * x[tk][jj];
    }
#pragma unroll
    for (int m = 1; m < 16; m <<= 1) {
#pragma unroll
      for (int tk = 0; tk < 4; ++tk) s[tk] += __shfl_xor(s[tk], m, 64);
    }
    const float sc = (MODE == 0 ? 0.08838834764831845f : 1.f);
    int head = tid >> 4, d0 = c0 & 127;
#pragma unroll
    for (int tk = 0; tk < 4; ++tk) {
      float rn = rsqrtf(s[tk] + 1e-6f) * sc;
#pragma unroll
      for (int jj = 0; jj < 8; ++jj) ov[jj] = f2b(x[tk][jj] * rn);
      *reinterpret_cast<uint4*>(outp + ((bt0 + tk) * 16 + head) * 128 + d0) =
          *reinterpret_cast<uint4*>(ov);
    }
  } else {
    int head = headbase + (c0 >> 7), d0 = c0 & 127;
#pragma unroll
    for (int tk = 0; tk < 4; ++tk) {
#pragma unroll
      for (int jj = 0; jj < 8; ++jj) ov[jj] = f2b(x[tk][jj]);
      *reinterpret_cast<uint4*>(outp + ((bt0 + tk) * 32 + head) * 128 + d0) =
          *reinterpret_cast<uint4*>(ov);
    }
  }
}

// -------- gates: beta/g from ba, cumsum g within chunks of 64 --------
__global__ __launch_bounds__(256) void gates_cumsum(const float* __restrict__ ba,
    const float* __restrict__ dt_bias, const float* __restrict__ A_log,
    float* __restrict__ bl_g, float* __restrict__ beta_g) {
  int widx = blockIdx.x * 4 + (threadIdx.x >> 6);
  int lane = threadIdx.x & 63;
  int bh = widx >> 6, chunk = widx & 63;
  int b = bh >> 5, h = bh & 31;
  size_t btl = (size_t)b * 4096 + chunk * 64 + lane;
  float bv = ba[btl * 64 + h];
  float av = ba[btl * 64 + 32 + h];
  float beta = 1.f / (1.f + __expf(-bv));
  float xx = av + dt_bias[h];
  float sp = (xx > 20.f) ? xx : log1pf(__expf(xx));
  float g = -__expf(A_log[h]) * sp;
#pragma unroll
  for (int off = 1; off < 64; off <<= 1) {
    float n = __shfl_up(g, off, 64);
    if (lane >= off) g += n;
  }
  bl_g[(size_t)widx * 64 + lane] = g;
  beta_g[(size_t)widx * 64 + lane] = beta;
}

// ---------------- MFMA tile helpers ----------------
static __device__ __forceinline__ f32x4 tile_range(const us* A, int lda,
    const us* B, int ldb, int rt, int ct, int l0, int nk, int lane, f32x4 acc) {
  const us* ar = A + (rt * 16 + (lane & 15)) * lda + l0 * 16 + (lane >> 4) * 8;
  const us* br = B + (ct * 16 + (lane & 15)) * ldb + l0 * 16 + (lane >> 4) * 8;
#pragma unroll
  for (int ks = 0; ks < nk; ++ks) {
    short8 a = *reinterpret_cast<const short8*>(ar + ks * 32);
    short8 bb = *reinterpret_cast<const short8*>(br + ks * 32);
    acc = __builtin_amdgcn_mfma_f32_16x16x32_bf16(a, bb, acc, 0, 0, 0);
  }
  return acc;
}
// swizzled variant: slot' = slot ^ ((row >> SA/SB) & 7); SA/SB < 0 => no swizzle
template <int SA, int SB>
static __device__ __forceinline__ f32x4 tile_swz(const us* A, int lda,
    const us* B, int ldb, int rt, int ct, int nk, int lane, f32x4 acc) {
  int ra = rt * 16 + (lane & 15);
  int rb = ct * 16 + (lane & 15);
  int j = lane >> 4;
#pragma unroll
  for (int ks = 0; ks < nk; ++ks) {
    int slot = j + 4 * ks;
    int oa = (SA >= 0) ? ((slot ^ ((ra >> (SA < 0 ? 0 : SA)) & 7)) * 8) : (slot * 8);
    int ob = (SB >= 0) ? ((slot ^ ((rb >> (SB < 0 ? 0 : SB)) & 7)) * 8) : (slot * 8);
    short8 a = *reinterpret_cast<const short8*>(A + ra * lda + oa);
    short8 bb = *reinterpret_cast<const short8*>(B + rb * ldb + ob);
    acc = __builtin_amdgcn_mfma_f32_16x16x32_bf16(a, bb, acc, 0, 0, 0);
  }
  return acc;
}

// =======================================================================
// Scan pass 1 (chunk-parallel): per (bh, chunk) compute T=(I+D)^-1 -> Tg.
// =======================================================================
__global__ __launch_bounds__(512, 1) void scan_p1(
    const us* __restrict__ k, const float* __restrict__ bl_g,
    const float* __restrict__ beta_g, us* __restrict__ Tg) {
  __shared__ us Kb[64 * 136];
  __shared__ us Ebt[64 * 72];
  __shared__ us W1[64 * 72], W1t[64 * 72], W3[64 * 72];
  __shared__ float bl_s[64], bet_s[64];
  us* const Eb = Kb;

  int bid = blockIdx.x, bh = bid >> 6, c = bid & 63;
  int b = bh >> 5, h = bh & 31, hk = h >> 1;
  int tid = threadIdx.x, w = tid >> 6, lane = tid & 63;
  int row = tid >> 3, c16 = (tid & 7) * 16;
  size_t bt0 = (size_t)b * 4096 + c * 64;

  const int TR_[10] = {0, 1, 1, 2, 2, 2, 3, 3, 3, 3};
  const int TC_[10] = {0, 0, 1, 0, 1, 2, 0, 1, 2, 3};

  const us* kp = k + ((bt0 + row) * 16 + hk) * 128 + c16;
  uint4 kr0 = reinterpret_cast<const uint4*>(kp)[0];
  uint4 kr1 = reinterpret_cast<const uint4*>(kp)[1];
  int gbase = (bh * 64 + c) * 64;
  if (tid < 64) { bl_s[tid] = bl_g[gbase + tid]; bet_s[tid] = beta_g[gbase + tid]; }
  *reinterpret_cast<uint4*>(&Kb[row * 136 + c16]) = kr0;
  *reinterpret_cast<uint4*>(&Kb[row * 136 + c16 + 8]) = kr1;
  __syncthreads();
  {
    int art = w & 3;
#pragma unroll
    for (int s = 0; s < 2; ++s) {
      int ct = (w >> 2) * 2 + s;
      f32x4 a = tile_range(Kb, 136, Kb, 136, art, ct, 0, 4, lane, f32x4{});
#pragma unroll
      for (int e = 0; e < 4; ++e) {
        int tr = art * 16 + (lane >> 4) * 4 + e;
        int cl = ct * 16 + (lane & 15);
        float dv = (cl < tr) ? bet_s[tr] * __expf(bl_s[tr] - bl_s[cl]) * a[e] : 0.f;
        W1[tr * 72 + cl] = f2b(dv);
        W1t[cl * 72 + tr] = f2b(dv);
        W3[tr * 72 + cl] = f2b((tr == cl ? 1.f : 0.f) - dv);
      }
    }
  }
  __syncthreads();
  f32x4 freg[2] = {};
#pragma unroll
  for (int it = 1; it <= 5; ++it) {
    if (it > 1) {
#pragma unroll
      for (int s = 0; s < 2; ++s) {
        int j = w + s * 8;
        if (j < 10) {
          int r = TR_[j], cc0 = TC_[j];
#pragma unroll
          for (int e = 0; e < 4; ++e) {
            int rr = r * 16 + (lane >> 4) * 4 + e, cl = cc0 * 16 + (lane & 15);
            W3[rr * 72 + cl] = f2b(b2f(W3[rr * 72 + cl]) + freg[s][e]);
          }
        }
      }
    }
    if (it == 1) {
      const int ZR[12] = {0, 0, 0, 1, 1, 2, 1, 2, 2, 3, 3, 3};
      const int ZC[12] = {1, 2, 3, 2, 3, 3, 0, 0, 1, 0, 1, 2};
#pragma unroll
      for (int u = 0; u < 12; ++u) {
        if ((u & 7) != w) continue;
        us* arr = (u < 6) ? Eb : Ebt;
        if (lane < 32) {
          int rr = ZR[u] * 16 + (lane >> 1);
          *reinterpret_cast<uint4*>(&arr[rr * 72 + ZC[u] * 16 + (lane & 1) * 8]) =
              make_uint4(0, 0, 0, 0);
        }
      }
    }
    const us* Es  = (it & 1) ? W1  : Eb;
    const us* Est = (it & 1) ? W1t : Ebt;
    us* Ed  = (it & 1) ? Eb  : W1;
    us* Edt = (it & 1) ? Ebt : W1t;
#pragma unroll
    for (int s = 0; s < 2; ++s) {
      int j = w + s * 8;
      if (j < 10) {
        int r = TR_[j], cc0 = TC_[j];
        int l0 = cc0 & ~1, nk = (r - l0 + 2) >> 1;
        f32x4 a = tile_range(Es, 72, Est, 72, r, cc0, l0, nk, lane, f32x4{});
#pragma unroll
        for (int e = 0; e < 4; ++e) {
          int rr = r * 16 + (lane >> 4) * 4 + e, cl = cc0 * 16 + (lane & 15);
          us val = f2b(a[e]);
          Ed[rr * 72 + cl] = val;
          Edt[cl * 72 + rr] = val;
        }
      }
    }
    __syncthreads();
    const us* Ent = (it & 1) ? Ebt : W1t;
#pragma unroll
    for (int s = 0; s < 2; ++s) {
      int j = w + s * 8;
      if (j < 10) {
        int r = TR_[j], cc0 = TC_[j];
        int l0 = cc0 & ~1, nk = (r - l0 + 2) >> 1;
        freg[s] = tile_range(W3, 72, Ent, 72, r, cc0, l0, nk, lane, f32x4{});
      }
    }
    __syncthreads();
  }
#pragma unroll
  for (int s = 0; s < 2; ++s) {
    int j = w + s * 8;
    if (j < 10) {
      int r = TR_[j], cc0 = TC_[j];
#pragma unroll
      for (int e = 0; e < 4; ++e) {
        int rr = r * 16 + (lane >> 4) * 4 + e, cl = cc0 * 16 + (lane & 15);
        W3[rr * 72 + cl] = f2b(b2f(W3[rr * 72 + cl]) + freg[s][e]);
      }
    }
  }
  __syncthreads();
  *reinterpret_cast<uint4*>(&Tg[(size_t)bid * 4096 + tid * 8]) =
      *reinterpret_cast<const uint4*>(&W3[row * 72 + (tid & 7) * 8]);
}

// =======================================================================
// Scan pass 2: sequential over chunks, 4x V-split (256 blocks).
// Swizzled Vt/Ut (slot ^ v>>3) + vectorized Ktb transpose (slot ^ d>>4).
// =======================================================================
__global__ __launch_bounds__(512, 1) void scan_p2(
    const us* __restrict__ q, const us* __restrict__ k, const us* __restrict__ v,
    const float* __restrict__ bl_g, const float* __restrict__ beta_g,
    const us* __restrict__ Tg, us* __restrict__ o) {
  __shared__ us Sb[32 * 136];
  __shared__ us Kb[64 * 136];
  __shared__ us Qb[64 * 136];
  __shared__ us Ktb[128 * 72];   // e^{bC-b_t} K^T [d][t], slot ^ (d>>4)
  __shared__ us Vt[32 * 72];     // [v][t], slot ^ (v>>3)
  __shared__ us Ut[32 * 72];     // [v][t], slot ^ (v>>3)
  __shared__ us W3[64 * 72];
  __shared__ us WP[64 * 72];
  __shared__ float bl_s[64], bet_s[64], ksc_s[64];

  int bid = blockIdx.x, vs = bid >> 6, bh = bid & 63;
  int b = bh >> 5, h = bh & 31, hk = h >> 1;
  int tid = threadIdx.x, w = tid >> 6, lane = tid & 63;
  int row = tid >> 3, c16 = (tid & 7) * 16;

  for (int i = tid; i < (32 * 136) / 8; i += 512)
    reinterpret_cast<uint4*>(Sb)[i] = make_uint4(0, 0, 0, 0);
  __syncthreads();

  uint4 kr0, kr1, qr0, qr1, vr, Tr;
  float blr, blC, bet, betv;
  int vrow = (tid & 255) >> 2, vseg = tid & 3;
  auto load_regs = [&](int c) {
    size_t bt0 = (size_t)b * 4096 + c * 64;
    const us* kp = k + ((bt0 + row) * 16 + hk) * 128 + c16;
    const us* qp = q + ((bt0 + row) * 16 + hk) * 128 + c16;
    kr0 = reinterpret_cast<const uint4*>(kp)[0];
    kr1 = reinterpret_cast<const uint4*>(kp)[1];
    qr0 = reinterpret_cast<const uint4*>(qp)[0];
    qr1 = reinterpret_cast<const uint4*>(qp)[1];
    Tr = *reinterpret_cast<const uint4*>(&Tg[((size_t)bh * 64 + c) * 4096 + tid * 8]);
    int gbase = (bh * 64 + c) * 64;
    blr = bl_g[gbase + row];
    blC = bl_g[gbase + 63];
    bet = beta_g[gbase + row];
    if (tid < 256) {
      vr = *reinterpret_cast<const uint4*>(
          v + ((bt0 + vrow) * 32 + h) * 128 + vs * 32 + vseg * 8);
      betv = beta_g[gbase + vrow];
    }
  };
  load_regs(0);

  for (int c = 0; c < 64; ++c) {
    size_t bt0 = (size_t)b * 4096 + c * 64;
    // ---- LF ----
    if ((tid & 7) == 0) {
      bl_s[row] = blr; bet_s[row] = bet;
      ksc_s[row] = __expf(blC - blr);
    }
    *reinterpret_cast<uint4*>(&Kb[row * 136 + c16]) = kr0;
    *reinterpret_cast<uint4*>(&Kb[row * 136 + c16 + 8]) = kr1;
    *reinterpret_cast<uint4*>(&Qb[row * 136 + c16]) = qr0;
    *reinterpret_cast<uint4*>(&Qb[row * 136 + c16 + 8]) = qr1;
    *reinterpret_cast<uint4*>(&W3[row * 72 + (tid & 7) * 8]) = Tr;
    if (tid < 256) {
      us vreg[8];
      *reinterpret_cast<uint4*>(vreg) = vr;
#pragma unroll
      for (int i = 0; i < 8; ++i) {
        int vv = vseg * 8 + i;
        Vt[vv * 72 + (((vrow >> 3) ^ vseg) & 7) * 8 + (vrow & 7)] = f2b(betv * b2f(vreg[i]));
      }
    }
    load_regs(c < 63 ? c + 1 : 63);
    bar_lds();
    // ---- G1: Ktb build + Q.S0 + P + RHS ----
#pragma unroll
    for (int tk = 0; tk < 2; ++tk) {
      int task = tid + tk * 512;
      int d = task & 127, oct = task >> 7;
      us kt[8];
#pragma unroll
      for (int i = 0; i < 8; ++i)
        kt[i] = f2b(ksc_s[oct * 8 + i] * b2f(Kb[(oct * 8 + i) * 136 + d]));
      *reinterpret_cast<uint4*>(&Ktb[d * 72 + ((oct ^ ((d >> 4) & 7)) * 8)]) =
          *reinterpret_cast<uint4*>(kt);
    }
    int rtO = w >> 1, ctv = w & 1;
    f32x4 o1 = tile_swz<-1, -1>(Qb, 136, Sb, 136, rtO, ctv, 4, lane, f32x4{});
    {
      int art = w & 3;
#pragma unroll
      for (int s = 0; s < 2; ++s) {
        int ct = (w >> 2) * 2 + s;
        f32x4 a = tile_swz<-1, -1>(Qb, 136, Kb, 136, art, ct, 4, lane, f32x4{});
#pragma unroll
        for (int e = 0; e < 4; ++e) {
          int tr = art * 16 + (lane >> 4) * 4 + e;
          int cl = ct * 16 + (lane & 15);
          float pv = (cl <= tr) ? __expf(bl_s[tr] - bl_s[cl]) * a[e] : 0.f;
          WP[tr * 72 + cl] = f2b(pv);
        }
      }
    }
    {
      int vrt = w >> 2, ct = w & 3;
      f32x4 a = tile_swz<-1, -1>(Sb, 136, Kb, 136, vrt, ct, 4, lane, f32x4{});
      int tt = ct * 16 + (lane & 15);
      float csc = bet_s[tt] * __expf(bl_s[tt]);
#pragma unroll
      for (int e = 0; e < 4; ++e) {
        int vv = vrt * 16 + (lane >> 4) * 4 + e;
        int off = vv * 72 + (((tt >> 3) ^ ((vv >> 3) & 7)) * 8) + (tt & 7);
        Vt[off] = f2b(b2f(Vt[off]) - csc * a[e]);
      }
    }
    bar_lds();
    // ---- G2: Ut = RHS^T . T^T ----
    {
      int vrt = w >> 2, ct = w & 3;
      f32x4 a = tile_swz<3, -1>(Vt, 72, W3, 72, vrt, ct, 2, lane, f32x4{});
#pragma unroll
      for (int e = 0; e < 4; ++e) {
        int uv = vrt * 16 + (lane >> 4) * 4 + e;
        int ut2 = ct * 16 + (lane & 15);
        Ut[uv * 72 + (((ut2 >> 3) ^ ((uv >> 3) & 7)) * 8) + (ut2 & 7)] = f2b(a[e]);
      }
    }
    bar_lds();
    // ---- OS: O write + S update ----
    float lamC = __expf(bl_s[63]);
    {
      f32x4 a = tile_swz<-1, 3>(WP, 72, Ut, 72, rtO, ctv, 2, lane, f32x4{});
#pragma unroll
      for (int e = 0; e < 4; ++e) {
        int tt = rtO * 16 + (lane >> 4) * 4 + e;
        int vv = vs * 32 + ctv * 16 + (lane & 15);
        float val = __expf(bl_s[tt]) * o1[e] + a[e];
        o[((bt0 + tt) * 32 + h) * 128 + vv] = f2b(val);
      }
    }
#pragma unroll
    for (int s = 0; s < 2; ++s) {
      int ti = w * 2 + s;
      int vrt = ti >> 3, dt = ti & 7;
      f32x4 a = tile_swz<3, 4>(Ut, 72, Ktb, 72, vrt, dt, 2, lane, f32x4{});
#pragma unroll
      for (int e = 0; e < 4; ++e) {
        int vv = vrt * 16 + (lane >> 4) * 4 + e, dd = dt * 16 + (lane & 15);
        Sb[vv * 136 + dd] = f2b(lamC * b2f(Sb[vv * 136 + dd]) + a[e]);
      }
    }
    bar_lds();
  }
}

// ---------------- gated RMSNorm, in place, vectorized ----------------
__global__ __launch_bounds__(256) void rms_gate(us* oy,
    const us* __restrict__ z, const float* __restrict__ nw) {
  int sub = threadIdx.x & 31;
  size_t row = (size_t)blockIdx.x * 8 + (threadIdx.x >> 5);
  size_t base = row * 128 + sub * 4;
  ushort4 ov = *reinterpret_cast<ushort4*>(oy + base);
  ushort4 zv = *reinterpret_cast<const ushort4*>(z + base);
  float o_[4] = {b2f(ov.x), b2f(ov.y), b2f(ov.z), b2f(ov.w)};
  float ss = o_[0] * o_[0] + o_[1] * o_[1] + o_[2] * o_[2] + o_[3] * o_[3];
#pragma unroll
  for (int m = 1; m < 32; m <<= 1) ss += __shfl_xor(ss, m, 64);
  float r = rsqrtf(ss * (1.f / 128.f) + 1e-6f);
  float4 w4 = *reinterpret_cast<const float4*>(nw + sub * 4);
  float zz[4] = {b2f(zv.x), b2f(zv.y), b2f(zv.z), b2f(zv.w)};
  float wv[4] = {w4.x, w4.y, w4.z, w4.w};
  us res[4];
#pragma unroll
  for (int i = 0; i < 4; ++i) {
    float zs = zz[i] / (1.f + __expf(-zz[i]));
    res[i] = f2b(o_[i] * r * wv[i] * zs);
  }
  *reinterpret_cast<ushort4*>(oy + base) = *reinterpret_cast<ushort4*>(res);
}

extern "C" void kernel_launch(void* const* d_in, const int* in_sizes, int n_in,
                              void* d_out, int out_size, void* d_ws, size_t ws_size,
                              hipStream_t stream) {
  const float* hs      = (const float*)d_in[0];
  const float* W_qkv   = (const float*)d_in[1];
  const float* W_z     = (const float*)d_in[2];
  const float* W_b     = (const float*)d_in[3];
  const float* W_a     = (const float*)d_in[4];
  const float* conv_w  = (const float*)d_in[5];
  const float* dt_bias = (const float*)d_in[6];
  const float* A_log   = (const float*)d_in[7];
  const float* norm_w  = (const float*)d_in[8];
  const float* W_out   = (const float*)d_in[9];
  float* out = (float*)d_out;

  char* ws = (char*)d_ws;
  const size_t MiB = 1u << 20;
  float* ba_buf = (float*)(ws);
  float* bl_g   = (float*)(ws + 2 * MiB);
  float* bt_g   = (float*)(ws + 3 * MiB);
  us*    wt     = (us*)(ws + 4 * MiB);
  us*    Tg     = (us*)(ws + 4 * MiB);
  us*    mixed  = (us*)(ws + 36 * MiB);
  us*    o_buf  = (us*)(ws + 36 * MiB);
  us*    hs_bf0 = (us*)(ws + 68 * MiB);
  us*    q_buf  = (us*)(ws + 100 * MiB);
  us*    hs_bf1 = q_buf;
  us*    k_buf  = (us*)(ws + 132 * MiB);
  us*    v_buf  = (us*)(ws + 164 * MiB);
  us*    z_bf   = v_buf;

  cvt_f32_bf16<<<2048, 256, 0, stream>>>(hs, hs_bf0, (long)8192 * 2048 / 4);

  for (int c = 0; c < 4; ++c) {
    transpose_cvt<<<dim3(32, 32), 256, 0, stream>>>(W_qkv, wt, 2048, 2048, 8192, c * 2048, 0);
    gemm256<true><<<dim3(32, 8), 512, 0, stream>>>(hs_bf0, wt, mixed, 2048, 2048);
    const float* cwc = conv_w + (size_t)c * 2048 * 4;
    if (c == 0)      conv_chunk<0><<<2048, 256, 0, stream>>>(mixed, cwc, q_buf, 0);
    else if (c == 1) conv_chunk<1><<<2048, 256, 0, stream>>>(mixed, cwc, k_buf, 0);
    else if (c == 2) conv_chunk<2><<<2048, 256, 0, stream>>>(mixed, cwc, v_buf, 0);
    else             conv_chunk<2><<<2048, 256, 0, stream>>>(mixed, cwc, v_buf, 16);
  }
  transpose_cvt<<<dim3(1, 32), 256, 0, stream>>>(W_b, wt, 2048, 32, 32, 0, 0);
  transpose_cvt<<<dim3(1, 32), 256, 0, stream>>>(W_a, wt, 2048, 32, 32, 0, 32);
  gemm_lds_f32<<<dim3(64, 1), 256, 0, stream>>>(hs_bf0, wt, ba_buf, 2048, 63, 64, 64);
  gates_cumsum<<<1024, 256, 0, stream>>>(ba_buf, dt_bias, A_log, bl_g, bt_g);
  scan_p1<<<4096, 512, 0, stream>>>(k_buf, bl_g, bt_g, Tg);
  scan_p2<<<256, 512, 0, stream>>>(q_buf, k_buf, v_buf, bl_g, bt_g, Tg, o_buf);
  cvt_f32_bf16<<<2048, 256, 0, stream>>>(hs, hs_bf1, (long)8192 * 2048 / 4);
  transpose_cvt<<<dim3(64, 32), 256, 0, stream>>>(W_z, wt, 2048, 4096, 4096, 0, 0);
  gemm256<true><<<dim3(32, 16), 512, 0, stream>>>(hs_bf1, wt, z_bf, 2048, 4096);
  rms_gate<<<32768, 256, 0, stream>>>(o_buf, z_bf, norm_w);
  transpose_cvt<<<dim3(32, 64), 256, 0, stream>>>(W_out, wt, 4096, 2048, 2048, 0, 0);
  gemm256<false><<<dim3(32, 8), 512, 0, stream>>>(o_buf, wt, out, 4096, 2048);
}

// Round 19
// 1051.181 us; speedup vs baseline: 1.1754x; 1.0033x over previous
//
#include <hip/hip_runtime.h>
#include <hip/hip_bf16.h>

// Qwen3.5 GatedDeltaNet: B=2, T=4096, D=2048, NV=32, NK=16, DK=DV=128, KC=4
// Round 19: scan_p2 LF merged into OS phase (4 -> 3 barriers/chunk; gates
// double-buffered; LF writes {Kb,Qb,W3,Vt} are dead during OS per liveness).
// W_qkv transpose hoisted to a single dispatch (into the Tg region, dead
// until scan_p1). Everything else = round 18 (best, 1054 us).

typedef __attribute__((ext_vector_type(8))) short short8;
typedef __attribute__((ext_vector_type(4))) float f32x4;
typedef unsigned short us;

static __device__ __forceinline__ us f2b(float f) {
  __hip_bfloat16 h = __float2bfloat16(f);
  return __builtin_bit_cast(us, h);
}
static __device__ __forceinline__ float b2f(us u) {
  return __bfloat162float(__builtin_bit_cast(__hip_bfloat16, u));
}
// barrier that publishes LDS (lgkmcnt) but leaves global loads/stores in flight
static __device__ __forceinline__ void bar_lds() {
  asm volatile("s_waitcnt lgkmcnt(0)" ::: "memory");
  __builtin_amdgcn_s_barrier();
}

// ---------------- fp32 -> bf16 elementwise ----------------
__global__ __launch_bounds__(256) void cvt_f32_bf16(const float* __restrict__ in,
    us* __restrict__ out, long n4) {
  long i = (long)blockIdx.x * 256 + threadIdx.x;
  long stride = (long)gridDim.x * 256;
  for (; i < n4; i += stride) {
    float4 f = reinterpret_cast<const float4*>(in)[i];
    ushort4 u;
    u.x = f2b(f.x); u.y = f2b(f.y); u.z = f2b(f.z); u.w = f2b(f.w);
    reinterpret_cast<ushort4*>(out)[i] = u;
  }
}

// ------- fp32 [K][Nfull] (col slice) -> bf16 [N][K] transpose, 64x64 tiles -------
__global__ __launch_bounds__(256) void transpose_cvt(const float* __restrict__ in,
    us* __restrict__ out, int K, int N, int Nfull, int coloff, int row_off) {
  __shared__ float tile[64][65];
  int tid = threadIdx.x;
  int n0 = blockIdx.x * 64, k0 = blockIdx.y * 64;
  int tx = tid & 15, ty = tid >> 4;
#pragma unroll
  for (int r = 0; r < 4; ++r) {
    int kk = k0 + ty + r * 16, nn = n0 + tx * 4;
    float4 v = make_float4(0.f, 0.f, 0.f, 0.f);
    if (kk < K && nn < N)
      v = *reinterpret_cast<const float4*>(in + (size_t)kk * Nfull + coloff + nn);
    tile[ty + r * 16][tx * 4 + 0] = v.x;
    tile[ty + r * 16][tx * 4 + 1] = v.y;
    tile[ty + r * 16][tx * 4 + 2] = v.z;
    tile[ty + r * 16][tx * 4 + 3] = v.w;
  }
  __syncthreads();
#pragma unroll
  for (int g = 0; g < 2; ++g) {
    int s = tid + g * 256;
    int nn = s >> 3, ks = (s & 7) * 8;
    if (n0 + nn < N && k0 + ks < K) {
      us ov[8];
#pragma unroll
      for (int i = 0; i < 8; ++i) ov[i] = f2b(tile[ks + i][nn]);
      *reinterpret_cast<uint4*>(out + (size_t)(n0 + nn + row_off) * K + k0 + ks) =
          *reinterpret_cast<uint4*>(ov);
    }
  }
}

// ================= 256x256 8-wave double-buffered TN GEMM (round-8) =================
template <bool BF16OUT>
__global__ __launch_bounds__(512, 1) void gemm256(const us* __restrict__ A,
    const us* __restrict__ B, void* __restrict__ Cout, int K, int ldC) {
  __shared__ us Abuf[2][256 * 64];
  __shared__ us Bbuf[2][256 * 64];
  int tid = threadIdx.x, w = tid >> 6, lane = tid & 63;
  int wr = w >> 2, wc = w & 3;
  int fr = lane & 15, j4 = lane >> 4;
  int lin = blockIdx.y * gridDim.x + blockIdx.x;
  int nwg = gridDim.x * gridDim.y;
  int wg = (lin & 7) * (nwg >> 3) + (lin >> 3);
  int bx = wg % gridDim.x, by = wg / gridDim.x;
  size_t bm = (size_t)bx * 256, bn = (size_t)by * 256;

  const us *aG[4], *bG[4];
  us *aL[2][4], *bL[2][4];
#pragma unroll
  for (int u = 0; u < 4; ++u) {
    int idx = u * 512 + tid;
    int row = idx >> 3, sl = idx & 7;
    int sg = (sl ^ (row & 7)) * 8;
    aG[u] = A + (bm + row) * K + sg;
    bG[u] = B + (bn + row) * K + sg;
    int lbase = (u * 64 + w * 8) * 64;
#pragma unroll
    for (int bf = 0; bf < 2; ++bf) {
      aL[bf][u] = &Abuf[bf][lbase];
      bL[bf][u] = &Bbuf[bf][lbase];
    }
  }

  f32x4 acc[8][4] = {};
#pragma unroll
  for (int u = 0; u < 4; ++u) {
    __builtin_amdgcn_global_load_lds((const void*)aG[u], (void*)aL[0][u], 16, 0, 0);
    __builtin_amdgcn_global_load_lds((const void*)bG[u], (void*)bL[0][u], 16, 0, 0);
  }
  __syncthreads();

  int nt = K >> 6;
  for (int t = 0; t < nt; ++t) {
    int cur = t & 1, nxt = cur ^ 1;
    const us* Ac = Abuf[cur];
    const us* Bc = Bbuf[cur];
    int kt1 = (t + 1) << 6;
    bool more = (t + 1 < nt);
#pragma unroll
    for (int q = 0; q < 4; ++q) {
      if (more) {
        __builtin_amdgcn_global_load_lds((const void*)(aG[q] + kt1), (void*)aL[nxt][q], 16, 0, 0);
        __builtin_amdgcn_global_load_lds((const void*)(bG[q] + kt1), (void*)bL[nxt][q], 16, 0, 0);
      }
      short8 a0[2], a1[2], bfv[4][2];
      int Ra0 = wr * 128 + 2 * q * 16 + fr;
      int Ra1 = Ra0 + 16;
#pragma unroll
      for (int ks = 0; ks < 2; ++ks) {
        a0[ks] = *reinterpret_cast<const short8*>(&Ac[Ra0 * 64 + (((ks * 4 + j4) ^ (Ra0 & 7)) * 8)]);
        a1[ks] = *reinterpret_cast<const short8*>(&Ac[Ra1 * 64 + (((ks * 4 + j4) ^ (Ra1 & 7)) * 8)]);
#pragma unroll
        for (int fj = 0; fj < 4; ++fj) {
          int Rb = wc * 64 + fj * 16 + fr;
          bfv[fj][ks] = *reinterpret_cast<const short8*>(&Bc[Rb * 64 + (((ks * 4 + j4) ^ (Rb & 7)) * 8)]);
        }
      }
      __builtin_amdgcn_s_setprio(1);
#pragma unroll
      for (int ks = 0; ks < 2; ++ks)
#pragma unroll
        for (int fj = 0; fj < 4; ++fj) {
          acc[2 * q][fj] = __builtin_amdgcn_mfma_f32_16x16x32_bf16(a0[ks], bfv[fj][ks], acc[2 * q][fj], 0, 0, 0);
          acc[2 * q + 1][fj] = __builtin_amdgcn_mfma_f32_16x16x32_bf16(a1[ks], bfv[fj][ks], acc[2 * q + 1][fj], 0, 0, 0);
        }
      __builtin_amdgcn_s_setprio(0);
    }
    __syncthreads();
  }
#pragma unroll
  for (int fi = 0; fi < 8; ++fi)
#pragma unroll
    for (int fj = 0; fj < 4; ++fj) {
      size_t col = bn + wc * 64 + fj * 16 + fr;
#pragma unroll
      for (int e = 0; e < 4; ++e) {
        size_t r = bm + wr * 128 + fi * 16 + j4 * 4 + e;
        size_t off = r * ldC + col;
        if (BF16OUT) reinterpret_cast<us*>(Cout)[off] = f2b(acc[fi][fj][e]);
        else reinterpret_cast<float*>(Cout)[off] = acc[fi][fj][e];
      }
    }
}

// ---------------- 128^2 GEMM (kept for the tiny ba projection) ----------------
__global__ __launch_bounds__(256) void gemm_lds_f32(const us* __restrict__ A,
    const us* __restrict__ B, float* __restrict__ Cout,
    int K, int Nb1, int Nvalid, int ldC) {
  __shared__ us Ash[128 * 64];
  __shared__ us Bsh[128 * 64];
  int tid = threadIdx.x, w = tid >> 6, lane = tid & 63;
  int bm = blockIdx.x * 128, bn = blockIdx.y * 128;
  int wm = (w >> 1) * 64, wn = (w & 1) * 64;
  const us* aP[4]; const us* bP[4]; us* lA[4]; us* lB[4];
#pragma unroll
  for (int i = 0; i < 4; ++i) {
    int idx = i * 256 + tid;
    int row = idx >> 3;
    int sg = ((idx & 7) ^ (row & 7)) * 8;
    aP[i] = A + (size_t)(bm + row) * K + sg;
    int rb = bn + row; if (rb > Nb1) rb = Nb1;
    bP[i] = B + (size_t)rb * K + sg;
    lA[i] = &Ash[(i * 256 + w * 64) * 8];
    lB[i] = &Bsh[(i * 256 + w * 64) * 8];
  }
  f32x4 acc[4][4] = {};
  int fr = lane & 15, j = lane >> 4;
  for (int kt = 0; kt < K; kt += 64) {
#pragma unroll
    for (int i = 0; i < 4; ++i)
      __builtin_amdgcn_global_load_lds((const void*)(aP[i] + kt), (void*)lA[i], 16, 0, 0);
#pragma unroll
    for (int i = 0; i < 4; ++i)
      __builtin_amdgcn_global_load_lds((const void*)(bP[i] + kt), (void*)lB[i], 16, 0, 0);
    __syncthreads();
#pragma unroll
    for (int ks = 0; ks < 2; ++ks) {
      short8 af[4], bfr[4];
#pragma unroll
      for (int f = 0; f < 4; ++f) {
        int Ra = wm + f * 16 + fr;
        af[f] = *reinterpret_cast<const short8*>(&Ash[Ra * 64 + (((ks * 4 + j) ^ (Ra & 7)) * 8)]);
        int Rb = wn + f * 16 + fr;
        bfr[f] = *reinterpret_cast<const short8*>(&Bsh[Rb * 64 + (((ks * 4 + j) ^ (Rb & 7)) * 8)]);
      }
#pragma unroll
      for (int i = 0; i < 4; ++i)
#pragma unroll
        for (int jj = 0; jj < 4; ++jj)
          acc[i][jj] = __builtin_amdgcn_mfma_f32_16x16x32_bf16(af[i], bfr[jj], acc[i][jj], 0, 0, 0);
    }
    __syncthreads();
  }
#pragma unroll
  for (int i = 0; i < 4; ++i)
#pragma unroll
    for (int jj = 0; jj < 4; ++jj) {
      int c0 = bn + wn + jj * 16 + (lane & 15);
      if (c0 < Nvalid) {
#pragma unroll
        for (int e = 0; e < 4; ++e) {
          int r = bm + wm + i * 16 + (lane >> 4) * 4 + e;
          Cout[(size_t)r * ldC + c0] = acc[i][jj][e];
        }
      }
    }
}

// -------- conv(KC=4)+silu (+l2norm), 4 tokens/block, 8 contiguous channels/thread --------
template <int MODE>
__global__ __launch_bounds__(256) void conv_chunk(const us* __restrict__ mixed,
    const float* __restrict__ cw, us* __restrict__ outp, int headbase) {
  int bp = blockIdx.x, b = bp >> 10, tloc = (bp & 1023) * 4, tid = threadIdx.x;
  int c0 = tid * 8;
  float wv[8][4];
#pragma unroll
  for (int jj = 0; jj < 8; ++jj) {
    float4 w4 = *reinterpret_cast<const float4*>(cw + (size_t)(c0 + jj) * 4);
    wv[jj][0] = w4.x; wv[jj][1] = w4.y; wv[jj][2] = w4.z; wv[jj][3] = w4.w;
  }
  us rw[7][8];
#pragma unroll
  for (int i = 0; i < 7; ++i) {
    int tt = tloc - 3 + i;
    if (tt >= 0 && tt < 4096)
      *reinterpret_cast<uint4*>(rw[i]) = *reinterpret_cast<const uint4*>(
          mixed + ((size_t)(b * 4096 + tt)) * 2048 + c0);
    else
      *reinterpret_cast<uint4*>(rw[i]) = make_uint4(0, 0, 0, 0);
  }
  float x[4][8];
#pragma unroll
  for (int jj = 0; jj < 8; ++jj) {
#pragma unroll
    for (int tk = 0; tk < 4; ++tk) {
      float a = 0.f;
#pragma unroll
      for (int i = 0; i < 4; ++i) a += b2f(rw[tk + i][jj]) * wv[jj][i];
      x[tk][jj] = a / (1.f + __expf(-a));
    }
  }
  size_t bt0 = (size_t)b * 4096 + tloc;
  us ov[8];
  if (MODE < 2) {
    float s[4] = {};
#pragma unroll
    for (int tk = 0; tk < 4; ++tk) {
#pragma unroll
      for (int jj = 0; jj < 8; ++jj) s[tk] += x[tk][jj] * x[tk][jj];
    }
#pragma unroll
    for (int m = 1; m < 16; m <<= 1) {
#pragma unroll
      for (int tk = 0; tk < 4; ++tk) s[tk] += __shfl_xor(s[tk], m, 64);
    }
    const float sc = (MODE == 0 ? 0.08838834764831845f : 1.f);
    int head = tid >> 4, d0 = c0 & 127;
#pragma unroll
    for (int tk = 0; tk < 4; ++tk) {
      float rn = rsqrtf(s[tk] + 1e-6f) * sc;
#pragma unroll
      for (int jj = 0; jj < 8; ++jj) ov[jj] = f2b(x[tk][jj] * rn);
      *reinterpret_cast<uint4*>(outp + ((bt0 + tk) * 16 + head) * 128 + d0) =
          *reinterpret_cast<uint4*>(ov);
    }
  } else {
    int head = headbase + (c0 >> 7), d0 = c0 & 127;
#pragma unroll
    for (int tk = 0; tk < 4; ++tk) {
#pragma unroll
      for (int jj = 0; jj < 8; ++jj) ov[jj] = f2b(x[tk][jj]);
      *reinterpret_cast<uint4*>(outp + ((bt0 + tk) * 32 + head) * 128 + d0) =
          *reinterpret_cast<uint4*>(ov);
    }
  }
}

// -------- gates: beta/g from ba, cumsum g within chunks of 64 --------
__global__ __launch_bounds__(256) void gates_cumsum(const float* __restrict__ ba,
    const float* __restrict__ dt_bias, const float* __restrict__ A_log,
    float* __restrict__ bl_g, float* __restrict__ beta_g) {
  int widx = blockIdx.x * 4 + (threadIdx.x >> 6);
  int lane = threadIdx.x & 63;
  int bh = widx >> 6, chunk = widx & 63;
  int b = bh >> 5, h = bh & 31;
  size_t btl = (size_t)b * 4096 + chunk * 64 + lane;
  float bv = ba[btl * 64 + h];
  float av = ba[btl * 64 + 32 + h];
  float beta = 1.f / (1.f + __expf(-bv));
  float xx = av + dt_bias[h];
  float sp = (xx > 20.f) ? xx : log1pf(__expf(xx));
  float g = -__expf(A_log[h]) * sp;
#pragma unroll
  for (int off = 1; off < 64; off <<= 1) {
    float n = __shfl_up(g, off, 64);
    if (lane >= off) g += n;
  }
  bl_g[(size_t)widx * 64 + lane] = g;
  beta_g[(size_t)widx * 64 + lane] = beta;
}

// ---------------- MFMA tile helpers ----------------
static __device__ __forceinline__ f32x4 tile_range(const us* A, int lda,
    const us* B, int ldb, int rt, int ct, int l0, int nk, int lane, f32x4 acc) {
  const us* ar = A + (rt * 16 + (lane & 15)) * lda + l0 * 16 + (lane >> 4) * 8;
  const us* br = B + (ct * 16 + (lane & 15)) * ldb + l0 * 16 + (lane >> 4) * 8;
#pragma unroll
  for (int ks = 0; ks < nk; ++ks) {
    short8 a = *reinterpret_cast<const short8*>(ar + ks * 32);
    short8 bb = *reinterpret_cast<const short8*>(br + ks * 32);
    acc = __builtin_amdgcn_mfma_f32_16x16x32_bf16(a, bb, acc, 0, 0, 0);
  }
  return acc;
}
// swizzled variant: slot' = slot ^ ((row >> SA/SB) & 7); SA/SB < 0 => no swizzle
template <int SA, int SB>
static __device__ __forceinline__ f32x4 tile_swz(const us* A, int lda,
    const us* B, int ldb, int rt, int ct, int nk, int lane, f32x4 acc) {
  int ra = rt * 16 + (lane & 15);
  int rb = ct * 16 + (lane & 15);
  int j = lane >> 4;
#pragma unroll
  for (int ks = 0; ks < nk; ++ks) {
    int slot = j + 4 * ks;
    int oa = (SA >= 0) ? ((slot ^ ((ra >> (SA < 0 ? 0 : SA)) & 7)) * 8) : (slot * 8);
    int ob = (SB >= 0) ? ((slot ^ ((rb >> (SB < 0 ? 0 : SB)) & 7)) * 8) : (slot * 8);
    short8 a = *reinterpret_cast<const short8*>(A + ra * lda + oa);
    short8 bb = *reinterpret_cast<const short8*>(B + rb * ldb + ob);
    acc = __builtin_amdgcn_mfma_f32_16x16x32_bf16(a, bb, acc, 0, 0, 0);
  }
  return acc;
}

// =======================================================================
// Scan pass 1 (chunk-parallel): per (bh, chunk) compute T=(I+D)^-1 -> Tg.
// =======================================================================
__global__ __launch_bounds__(512, 1) void scan_p1(
    const us* __restrict__ k, const float* __restrict__ bl_g,
    const float* __restrict__ beta_g, us* __restrict__ Tg) {
  __shared__ us Kb[64 * 136];
  __shared__ us Ebt[64 * 72];
  __shared__ us W1[64 * 72], W1t[64 * 72], W3[64 * 72];
  __shared__ float bl_s[64], bet_s[64];
  us* const Eb = Kb;

  int bid = blockIdx.x, bh = bid >> 6, c = bid & 63;
  int b = bh >> 5, h = bh & 31, hk = h >> 1;
  int tid = threadIdx.x, w = tid >> 6, lane = tid & 63;
  int row = tid >> 3, c16 = (tid & 7) * 16;
  size_t bt0 = (size_t)b * 4096 + c * 64;

  const int TR_[10] = {0, 1, 1, 2, 2, 2, 3, 3, 3, 3};
  const int TC_[10] = {0, 0, 1, 0, 1, 2, 0, 1, 2, 3};

  const us* kp = k + ((bt0 + row) * 16 + hk) * 128 + c16;
  uint4 kr0 = reinterpret_cast<const uint4*>(kp)[0];
  uint4 kr1 = reinterpret_cast<const uint4*>(kp)[1];
  int gbase = (bh * 64 + c) * 64;
  if (tid < 64) { bl_s[tid] = bl_g[gbase + tid]; bet_s[tid] = beta_g[gbase + tid]; }
  *reinterpret_cast<uint4*>(&Kb[row * 136 + c16]) = kr0;
  *reinterpret_cast<uint4*>(&Kb[row * 136 + c16 + 8]) = kr1;
  __syncthreads();
  {
    int art = w & 3;
#pragma unroll
    for (int s = 0; s < 2; ++s) {
      int ct = (w >> 2) * 2 + s;
      f32x4 a = tile_range(Kb, 136, Kb, 136, art, ct, 0, 4, lane, f32x4{});
#pragma unroll
      for (int e = 0; e < 4; ++e) {
        int tr = art * 16 + (lane >> 4) * 4 + e;
        int cl = ct * 16 + (lane & 15);
        float dv = (cl < tr) ? bet_s[tr] * __expf(bl_s[tr] - bl_s[cl]) * a[e] : 0.f;
        W1[tr * 72 + cl] = f2b(dv);
        W1t[cl * 72 + tr] = f2b(dv);
        W3[tr * 72 + cl] = f2b((tr == cl ? 1.f : 0.f) - dv);
      }
    }
  }
  __syncthreads();
  f32x4 freg[2] = {};
#pragma unroll
  for (int it = 1; it <= 5; ++it) {
    if (it > 1) {
#pragma unroll
      for (int s = 0; s < 2; ++s) {
        int j = w + s * 8;
        if (j < 10) {
          int r = TR_[j], cc0 = TC_[j];
#pragma unroll
          for (int e = 0; e < 4; ++e) {
            int rr = r * 16 + (lane >> 4) * 4 + e, cl = cc0 * 16 + (lane & 15);
            W3[rr * 72 + cl] = f2b(b2f(W3[rr * 72 + cl]) + freg[s][e]);
          }
        }
      }
    }
    if (it == 1) {
      const int ZR[12] = {0, 0, 0, 1, 1, 2, 1, 2, 2, 3, 3, 3};
      const int ZC[12] = {1, 2, 3, 2, 3, 3, 0, 0, 1, 0, 1, 2};
#pragma unroll
      for (int u = 0; u < 12; ++u) {
        if ((u & 7) != w) continue;
        us* arr = (u < 6) ? Eb : Ebt;
        if (lane < 32) {
          int rr = ZR[u] * 16 + (lane >> 1);
          *reinterpret_cast<uint4*>(&arr[rr * 72 + ZC[u] * 16 + (lane & 1) * 8]) =
              make_uint4(0, 0, 0, 0);
        }
      }
    }
    const us* Es  = (it & 1) ? W1  : Eb;
    const us* Est = (it & 1) ? W1t : Ebt;
    us* Ed  = (it & 1) ? Eb  : W1;
    us* Edt = (it & 1) ? Ebt : W1t;
#pragma unroll
    for (int s = 0; s < 2; ++s) {
      int j = w + s * 8;
      if (j < 10) {
        int r = TR_[j], cc0 = TC_[j];
        int l0 = cc0 & ~1, nk = (r - l0 + 2) >> 1;
        f32x4 a = tile_range(Es, 72, Est, 72, r, cc0, l0, nk, lane, f32x4{});
#pragma unroll
        for (int e = 0; e < 4; ++e) {
          int rr = r * 16 + (lane >> 4) * 4 + e, cl = cc0 * 16 + (lane & 15);
          us val = f2b(a[e]);
          Ed[rr * 72 + cl] = val;
          Edt[cl * 72 + rr] = val;
        }
      }
    }
    __syncthreads();
    const us* Ent = (it & 1) ? Ebt : W1t;
#pragma unroll
    for (int s = 0; s < 2; ++s) {
      int j = w + s * 8;
      if (j < 10) {
        int r = TR_[j], cc0 = TC_[j];
        int l0 = cc0 & ~1, nk = (r - l0 + 2) >> 1;
        freg[s] = tile_range(W3, 72, Ent, 72, r, cc0, l0, nk, lane, f32x4{});
      }
    }
    __syncthreads();
  }
#pragma unroll
  for (int s = 0; s < 2; ++s) {
    int j = w + s * 8;
    if (j < 10) {
      int r = TR_[j], cc0 = TC_[j];
#pragma unroll
      for (int e = 0; e < 4; ++e) {
        int rr = r * 16 + (lane >> 4) * 4 + e, cl = cc0 * 16 + (lane & 15);
        W3[rr * 72 + cl] = f2b(b2f(W3[rr * 72 + cl]) + freg[s][e]);
      }
    }
  }
  __syncthreads();
  *reinterpret_cast<uint4*>(&Tg[(size_t)bid * 4096 + tid * 8]) =
      *reinterpret_cast<const uint4*>(&W3[row * 72 + (tid & 7) * 8]);
}

// =======================================================================
// Scan pass 2: sequential over chunks, 4x V-split (256 blocks).
// 3 barriers/chunk: LF(c+1) merged into OS(c) (disjoint LDS buffers);
// gates double-buffered. Swizzled Vt/Ut + vectorized Ktb (round-13).
// =======================================================================
__global__ __launch_bounds__(512, 1) void scan_p2(
    const us* __restrict__ q, const us* __restrict__ k, const us* __restrict__ v,
    const float* __restrict__ bl_g, const float* __restrict__ beta_g,
    const us* __restrict__ Tg, us* __restrict__ o) {
  __shared__ us Sb[32 * 136];
  __shared__ us Kb[64 * 136];
  __shared__ us Qb[64 * 136];
  __shared__ us Ktb[128 * 72];   // e^{bC-b_t} K^T [d][t], slot ^ (d>>4)
  __shared__ us Vt[32 * 72];     // [v][t], slot ^ (v>>3)
  __shared__ us Ut[32 * 72];     // [v][t], slot ^ (v>>3)
  __shared__ us W3[64 * 72];
  __shared__ us WP[64 * 72];
  __shared__ float bl_s[2][64], bet_s[2][64], ksc_s[2][64];

  int bid = blockIdx.x, vs = bid >> 6, bh = bid & 63;
  int b = bh >> 5, h = bh & 31, hk = h >> 1;
  int tid = threadIdx.x, w = tid >> 6, lane = tid & 63;
  int row = tid >> 3, c16 = (tid & 7) * 16;

  for (int i = tid; i < (32 * 136) / 8; i += 512)
    reinterpret_cast<uint4*>(Sb)[i] = make_uint4(0, 0, 0, 0);

  uint4 kr0, kr1, qr0, qr1, vr, Tr;
  float blr, blC, bet, betv;
  int vrow = (tid & 255) >> 2, vseg = tid & 3;
  auto load_regs = [&](int c) {
    size_t bt0 = (size_t)b * 4096 + c * 64;
    const us* kp = k + ((bt0 + row) * 16 + hk) * 128 + c16;
    const us* qp = q + ((bt0 + row) * 16 + hk) * 128 + c16;
    kr0 = reinterpret_cast<const uint4*>(kp)[0];
    kr1 = reinterpret_cast<const uint4*>(kp)[1];
    qr0 = reinterpret_cast<const uint4*>(qp)[0];
    qr1 = reinterpret_cast<const uint4*>(qp)[1];
    Tr = *reinterpret_cast<const uint4*>(&Tg[((size_t)bh * 64 + c) * 4096 + tid * 8]);
    int gbase = (bh * 64 + c) * 64;
    blr = bl_g[gbase + row];
    blC = bl_g[gbase + 63];
    bet = beta_g[gbase + row];
    if (tid < 256) {
      vr = *reinterpret_cast<const uint4*>(
          v + ((bt0 + vrow) * 32 + h) * 128 + vs * 32 + vseg * 8);
      betv = beta_g[gbase + vrow];
    }
  };
  // write current regs (chunk cc) into the LDS staging buffers + gates[cc&1]
  auto lf_write = [&](int cc) {
    int pcw = cc & 1;
    if ((tid & 7) == 0) {
      bl_s[pcw][row] = blr; bet_s[pcw][row] = bet;
      ksc_s[pcw][row] = __expf(blC - blr);
    }
    *reinterpret_cast<uint4*>(&Kb[row * 136 + c16]) = kr0;
    *reinterpret_cast<uint4*>(&Kb[row * 136 + c16 + 8]) = kr1;
    *reinterpret_cast<uint4*>(&Qb[row * 136 + c16]) = qr0;
    *reinterpret_cast<uint4*>(&Qb[row * 136 + c16 + 8]) = qr1;
    *reinterpret_cast<uint4*>(&W3[row * 72 + (tid & 7) * 8]) = Tr;
    if (tid < 256) {
      us vreg[8];
      *reinterpret_cast<uint4*>(vreg) = vr;
#pragma unroll
      for (int i = 0; i < 8; ++i) {
        int vv = vseg * 8 + i;
        Vt[vv * 72 + (((vrow >> 3) ^ vseg) & 7) * 8 + (vrow & 7)] = f2b(betv * b2f(vreg[i]));
      }
    }
  };

  load_regs(0);
  lf_write(0);
  load_regs(1);
  bar_lds();  // publishes Sb init + LF(0)

  for (int c = 0; c < 64; ++c) {
    int pc = c & 1;
    size_t bt0 = (size_t)b * 4096 + c * 64;
    // ---- G1: Ktb build + Q.S0 + P + RHS ----
#pragma unroll
    for (int tk = 0; tk < 2; ++tk) {
      int task = tid + tk * 512;
      int d = task & 127, oct = task >> 7;
      us kt[8];
#pragma unroll
      for (int i = 0; i < 8; ++i)
        kt[i] = f2b(ksc_s[pc][oct * 8 + i] * b2f(Kb[(oct * 8 + i) * 136 + d]));
      *reinterpret_cast<uint4*>(&Ktb[d * 72 + ((oct ^ ((d >> 4) & 7)) * 8)]) =
          *reinterpret_cast<uint4*>(kt);
    }
    int rtO = w >> 1, ctv = w & 1;
    f32x4 o1 = tile_swz<-1, -1>(Qb, 136, Sb, 136, rtO, ctv, 4, lane, f32x4{});
    {
      int art = w & 3;
#pragma unroll
      for (int s = 0; s < 2; ++s) {
        int ct = (w >> 2) * 2 + s;
        f32x4 a = tile_swz<-1, -1>(Qb, 136, Kb, 136, art, ct, 4, lane, f32x4{});
#pragma unroll
        for (int e = 0; e < 4; ++e) {
          int tr = art * 16 + (lane >> 4) * 4 + e;
          int cl = ct * 16 + (lane & 15);
          float pv = (cl <= tr) ? __expf(bl_s[pc][tr] - bl_s[pc][cl]) * a[e] : 0.f;
          WP[tr * 72 + cl] = f2b(pv);
        }
      }
    }
    {
      int vrt = w >> 2, ct = w & 3;
      f32x4 a = tile_swz<-1, -1>(Sb, 136, Kb, 136, vrt, ct, 4, lane, f32x4{});
      int tt = ct * 16 + (lane & 15);
      float csc = bet_s[pc][tt] * __expf(bl_s[pc][tt]);
#pragma unroll
      for (int e = 0; e < 4; ++e) {
        int vv = vrt * 16 + (lane >> 4) * 4 + e;
        int off = vv * 72 + (((tt >> 3) ^ ((vv >> 3) & 7)) * 8) + (tt & 7);
        Vt[off] = f2b(b2f(Vt[off]) - csc * a[e]);
      }
    }
    bar_lds();
    // ---- G2: Ut = RHS^T . T^T ----
    {
      int vrt = w >> 2, ct = w & 3;
      f32x4 a = tile_swz<3, -1>(Vt, 72, W3, 72, vrt, ct, 2, lane, f32x4{});
#pragma unroll
      for (int e = 0; e < 4; ++e) {
        int uv = vrt * 16 + (lane >> 4) * 4 + e;
        int ut2 = ct * 16 + (lane & 15);
        Ut[uv * 72 + (((ut2 >> 3) ^ ((uv >> 3) & 7)) * 8) + (ut2 & 7)] = f2b(a[e]);
      }
    }
    bar_lds();
    // ---- OS: O write + S update, overlapped with LF(c+1) ----
    float lamC = __expf(bl_s[pc][63]);
    {
      f32x4 a = tile_swz<-1, 3>(WP, 72, Ut, 72, rtO, ctv, 2, lane, f32x4{});
#pragma unroll
      for (int e = 0; e < 4; ++e) {
        int tt = rtO * 16 + (lane >> 4) * 4 + e;
        int vv = vs * 32 + ctv * 16 + (lane & 15);
        float val = __expf(bl_s[pc][tt]) * o1[e] + a[e];
        o[((bt0 + tt) * 32 + h) * 128 + vv] = f2b(val);
      }
    }
#pragma unroll
    for (int s = 0; s < 2; ++s) {
      int ti = w * 2 + s;
      int vrt = ti >> 3, dt = ti & 7;
      f32x4 a = tile_swz<3, 4>(Ut, 72, Ktb, 72, vrt, dt, 2, lane, f32x4{});
#pragma unroll
      for (int e = 0; e < 4; ++e) {
        int vv = vrt * 16 + (lane >> 4) * 4 + e, dd = dt * 16 + (lane & 15);
        Sb[vv * 136 + dd] = f2b(lamC * b2f(Sb[vv * 136 + dd]) + a[e]);
      }
    }
    if (c < 63) {
      lf_write(c + 1);                       // writes Kb/Qb/W3/Vt + gates[!pc]
      load_regs(c + 2 <= 63 ? c + 2 : 63);   // prefetch next-next chunk
    }
    bar_lds();
  }
}

// ---------------- gated RMSNorm, in place, vectorized ----------------
__global__ __launch_bounds__(256) void rms_gate(us* oy,
    const us* __restrict__ z, const float* __restrict__ nw) {
  int sub = threadIdx.x & 31;
  size_t row = (size_t)blockIdx.x * 8 + (threadIdx.x >> 5);
  size_t base = row * 128 + sub * 4;
  ushort4 ov = *reinterpret_cast<ushort4*>(oy + base);
  ushort4 zv = *reinterpret_cast<const ushort4*>(z + base);
  float o_[4] = {b2f(ov.x), b2f(ov.y), b2f(ov.z), b2f(ov.w)};
  float ss = o_[0] * o_[0] + o_[1] * o_[1] + o_[2] * o_[2] + o_[3] * o_[3];
#pragma unroll
  for (int m = 1; m < 32; m <<= 1) ss += __shfl_xor(ss, m, 64);
  float r = rsqrtf(ss * (1.f / 128.f) + 1e-6f);
  float4 w4 = *reinterpret_cast<const float4*>(nw + sub * 4);
  float zz[4] = {b2f(zv.x), b2f(zv.y), b2f(zv.z), b2f(zv.w)};
  float wv[4] = {w4.x, w4.y, w4.z, w4.w};
  us res[4];
#pragma unroll
  for (int i = 0; i < 4; ++i) {
    float zs = zz[i] / (1.f + __expf(-zz[i]));
    res[i] = f2b(o_[i] * r * wv[i] * zs);
  }
  *reinterpret_cast<ushort4*>(oy + base) = *reinterpret_cast<ushort4*>(res);
}

extern "C" void kernel_launch(void* const* d_in, const int* in_sizes, int n_in,
                              void* d_out, int out_size, void* d_ws, size_t ws_size,
                              hipStream_t stream) {
  const float* hs      = (const float*)d_in[0];
  const float* W_qkv   = (const float*)d_in[1];
  const float* W_z     = (const float*)d_in[2];
  const float* W_b     = (const float*)d_in[3];
  const float* W_a     = (const float*)d_in[4];
  const float* conv_w  = (const float*)d_in[5];
  const float* dt_bias = (const float*)d_in[6];
  const float* A_log   = (const float*)d_in[7];
  const float* norm_w  = (const float*)d_in[8];
  const float* W_out   = (const float*)d_in[9];
  float* out = (float*)d_out;

  char* ws = (char*)d_ws;
  const size_t MiB = 1u << 20;
  // layout (MiB), peak 228 (proven safe):
  //  0-2 ba | 2-3 bl | 3-4 bt
  //  4-36: W_qkv^T (32 MiB) -> Tg (scan) -> W_z^T / W_out^T (post-scan)
  //  36-68 mixed (ba's tiny W^T reuses 36-36.25 after convs) \__ 36-100 o
  //  68-100 hs_bf0                                            /
  //  100-132 q -> hs_bf1 | 132-164 k | 164-228 v -> z
  float* ba_buf = (float*)(ws);
  float* bl_g   = (float*)(ws + 2 * MiB);
  float* bt_g   = (float*)(ws + 3 * MiB);
  us*    wt     = (us*)(ws + 4 * MiB);
  us*    Tg     = (us*)(ws + 4 * MiB);
  us*    mixed  = (us*)(ws + 36 * MiB);
  us*    wt_sm  = (us*)(ws + 36 * MiB);
  us*    o_buf  = (us*)(ws + 36 * MiB);
  us*    hs_bf0 = (us*)(ws + 68 * MiB);
  us*    q_buf  = (us*)(ws + 100 * MiB);
  us*    hs_bf1 = q_buf;
  us*    k_buf  = (us*)(ws + 132 * MiB);
  us*    v_buf  = (us*)(ws + 164 * MiB);
  us*    z_bf   = v_buf;

  cvt_f32_bf16<<<2048, 256, 0, stream>>>(hs, hs_bf0, (long)8192 * 2048 / 4);

  // full W_qkv^T in one dispatch (into 4-36, dead until scan_p1 writes Tg)
  transpose_cvt<<<dim3(128, 32), 256, 0, stream>>>(W_qkv, wt, 2048, 8192, 8192, 0, 0);
  for (int c = 0; c < 4; ++c) {
    gemm256<true><<<dim3(32, 8), 512, 0, stream>>>(
        hs_bf0, wt + (size_t)c * 2048 * 2048, mixed, 2048, 2048);
    const float* cwc = conv_w + (size_t)c * 2048 * 4;
    if (c == 0)      conv_chunk<0><<<2048, 256, 0, stream>>>(mixed, cwc, q_buf, 0);
    else if (c == 1) conv_chunk<1><<<2048, 256, 0, stream>>>(mixed, cwc, k_buf, 0);
    else if (c == 2) conv_chunk<2><<<2048, 256, 0, stream>>>(mixed, cwc, v_buf, 0);
    else             conv_chunk<2><<<2048, 256, 0, stream>>>(mixed, cwc, v_buf, 16);
  }
  // beta/a projections (tiny W^T into dead mixed region) + gates
  transpose_cvt<<<dim3(1, 32), 256, 0, stream>>>(W_b, wt_sm, 2048, 32, 32, 0, 0);
  transpose_cvt<<<dim3(1, 32), 256, 0, stream>>>(W_a, wt_sm, 2048, 32, 32, 0, 32);
  gemm_lds_f32<<<dim3(64, 1), 256, 0, stream>>>(hs_bf0, wt_sm, ba_buf, 2048, 63, 64, 64);
  gates_cumsum<<<1024, 256, 0, stream>>>(ba_buf, dt_bias, A_log, bl_g, bt_g);
  // two-pass chunked delta-rule scan
  scan_p1<<<4096, 512, 0, stream>>>(k_buf, bl_g, bt_g, Tg);
  scan_p2<<<256, 512, 0, stream>>>(q_buf, k_buf, v_buf, bl_g, bt_g, Tg, o_buf);
  // z projection
  cvt_f32_bf16<<<2048, 256, 0, stream>>>(hs, hs_bf1, (long)8192 * 2048 / 4);
  transpose_cvt<<<dim3(64, 32), 256, 0, stream>>>(W_z, wt, 2048, 4096, 4096, 0, 0);
  gemm256<true><<<dim3(32, 16), 512, 0, stream>>>(hs_bf1, wt, z_bf, 2048, 4096);
  rms_gate<<<32768, 256, 0, stream>>>(o_buf, z_bf, norm_w);
  // output projection
  transpose_cvt<<<dim3(32, 64), 256, 0, stream>>>(W_out, wt, 4096, 2048, 2048, 0, 0);
  gemm256<false><<<dim3(32, 8), 512, 0, stream>>>(o_buf, wt, out, 4096, 2048);
}

// Round 20
// 1031.662 us; speedup vs baseline: 1.1977x; 1.0189x over previous
//
#include <hip/hip_runtime.h>
#include <hip/hip_bf16.h>

// Qwen3.5 GatedDeltaNet: B=2, T=4096, D=2048, NV=32, NK=16, DK=DV=128, KC=4
// Round 20: o aliased onto v (per-block column slices disjoint; identical
// layout) -> hs_bf survives the scan -> second cvt dispatch deleted; z into
// the dead Tg+mixed region (4-68), W_z^T/W_out^T into dead q (100-132).
// All kernels byte-identical to round 19 (best, 1051 us).

typedef __attribute__((ext_vector_type(8))) short short8;
typedef __attribute__((ext_vector_type(4))) float f32x4;
typedef unsigned short us;

static __device__ __forceinline__ us f2b(float f) {
  __hip_bfloat16 h = __float2bfloat16(f);
  return __builtin_bit_cast(us, h);
}
static __device__ __forceinline__ float b2f(us u) {
  return __bfloat162float(__builtin_bit_cast(__hip_bfloat16, u));
}
// barrier that publishes LDS (lgkmcnt) but leaves global loads/stores in flight
static __device__ __forceinline__ void bar_lds() {
  asm volatile("s_waitcnt lgkmcnt(0)" ::: "memory");
  __builtin_amdgcn_s_barrier();
}

// ---------------- fp32 -> bf16 elementwise ----------------
__global__ __launch_bounds__(256) void cvt_f32_bf16(const float* __restrict__ in,
    us* __restrict__ out, long n4) {
  long i = (long)blockIdx.x * 256 + threadIdx.x;
  long stride = (long)gridDim.x * 256;
  for (; i < n4; i += stride) {
    float4 f = reinterpret_cast<const float4*>(in)[i];
    ushort4 u;
    u.x = f2b(f.x); u.y = f2b(f.y); u.z = f2b(f.z); u.w = f2b(f.w);
    reinterpret_cast<ushort4*>(out)[i] = u;
  }
}

// ------- fp32 [K][Nfull] (col slice) -> bf16 [N][K] transpose, 64x64 tiles -------
__global__ __launch_bounds__(256) void transpose_cvt(const float* __restrict__ in,
    us* __restrict__ out, int K, int N, int Nfull, int coloff, int row_off) {
  __shared__ float tile[64][65];
  int tid = threadIdx.x;
  int n0 = blockIdx.x * 64, k0 = blockIdx.y * 64;
  int tx = tid & 15, ty = tid >> 4;
#pragma unroll
  for (int r = 0; r < 4; ++r) {
    int kk = k0 + ty + r * 16, nn = n0 + tx * 4;
    float4 v = make_float4(0.f, 0.f, 0.f, 0.f);
    if (kk < K && nn < N)
      v = *reinterpret_cast<const float4*>(in + (size_t)kk * Nfull + coloff + nn);
    tile[ty + r * 16][tx * 4 + 0] = v.x;
    tile[ty + r * 16][tx * 4 + 1] = v.y;
    tile[ty + r * 16][tx * 4 + 2] = v.z;
    tile[ty + r * 16][tx * 4 + 3] = v.w;
  }
  __syncthreads();
#pragma unroll
  for (int g = 0; g < 2; ++g) {
    int s = tid + g * 256;
    int nn = s >> 3, ks = (s & 7) * 8;
    if (n0 + nn < N && k0 + ks < K) {
      us ov[8];
#pragma unroll
      for (int i = 0; i < 8; ++i) ov[i] = f2b(tile[ks + i][nn]);
      *reinterpret_cast<uint4*>(out + (size_t)(n0 + nn + row_off) * K + k0 + ks) =
          *reinterpret_cast<uint4*>(ov);
    }
  }
}

// ================= 256x256 8-wave double-buffered TN GEMM (round-8) =================
template <bool BF16OUT>
__global__ __launch_bounds__(512, 1) void gemm256(const us* __restrict__ A,
    const us* __restrict__ B, void* __restrict__ Cout, int K, int ldC) {
  __shared__ us Abuf[2][256 * 64];
  __shared__ us Bbuf[2][256 * 64];
  int tid = threadIdx.x, w = tid >> 6, lane = tid & 63;
  int wr = w >> 2, wc = w & 3;
  int fr = lane & 15, j4 = lane >> 4;
  int lin = blockIdx.y * gridDim.x + blockIdx.x;
  int nwg = gridDim.x * gridDim.y;
  int wg = (lin & 7) * (nwg >> 3) + (lin >> 3);
  int bx = wg % gridDim.x, by = wg / gridDim.x;
  size_t bm = (size_t)bx * 256, bn = (size_t)by * 256;

  const us *aG[4], *bG[4];
  us *aL[2][4], *bL[2][4];
#pragma unroll
  for (int u = 0; u < 4; ++u) {
    int idx = u * 512 + tid;
    int row = idx >> 3, sl = idx & 7;
    int sg = (sl ^ (row & 7)) * 8;
    aG[u] = A + (bm + row) * K + sg;
    bG[u] = B + (bn + row) * K + sg;
    int lbase = (u * 64 + w * 8) * 64;
#pragma unroll
    for (int bf = 0; bf < 2; ++bf) {
      aL[bf][u] = &Abuf[bf][lbase];
      bL[bf][u] = &Bbuf[bf][lbase];
    }
  }

  f32x4 acc[8][4] = {};
#pragma unroll
  for (int u = 0; u < 4; ++u) {
    __builtin_amdgcn_global_load_lds((const void*)aG[u], (void*)aL[0][u], 16, 0, 0);
    __builtin_amdgcn_global_load_lds((const void*)bG[u], (void*)bL[0][u], 16, 0, 0);
  }
  __syncthreads();

  int nt = K >> 6;
  for (int t = 0; t < nt; ++t) {
    int cur = t & 1, nxt = cur ^ 1;
    const us* Ac = Abuf[cur];
    const us* Bc = Bbuf[cur];
    int kt1 = (t + 1) << 6;
    bool more = (t + 1 < nt);
#pragma unroll
    for (int q = 0; q < 4; ++q) {
      if (more) {
        __builtin_amdgcn_global_load_lds((const void*)(aG[q] + kt1), (void*)aL[nxt][q], 16, 0, 0);
        __builtin_amdgcn_global_load_lds((const void*)(bG[q] + kt1), (void*)bL[nxt][q], 16, 0, 0);
      }
      short8 a0[2], a1[2], bfv[4][2];
      int Ra0 = wr * 128 + 2 * q * 16 + fr;
      int Ra1 = Ra0 + 16;
#pragma unroll
      for (int ks = 0; ks < 2; ++ks) {
        a0[ks] = *reinterpret_cast<const short8*>(&Ac[Ra0 * 64 + (((ks * 4 + j4) ^ (Ra0 & 7)) * 8)]);
        a1[ks] = *reinterpret_cast<const short8*>(&Ac[Ra1 * 64 + (((ks * 4 + j4) ^ (Ra1 & 7)) * 8)]);
#pragma unroll
        for (int fj = 0; fj < 4; ++fj) {
          int Rb = wc * 64 + fj * 16 + fr;
          bfv[fj][ks] = *reinterpret_cast<const short8*>(&Bc[Rb * 64 + (((ks * 4 + j4) ^ (Rb & 7)) * 8)]);
        }
      }
      __builtin_amdgcn_s_setprio(1);
#pragma unroll
      for (int ks = 0; ks < 2; ++ks)
#pragma unroll
        for (int fj = 0; fj < 4; ++fj) {
          acc[2 * q][fj] = __builtin_amdgcn_mfma_f32_16x16x32_bf16(a0[ks], bfv[fj][ks], acc[2 * q][fj], 0, 0, 0);
          acc[2 * q + 1][fj] = __builtin_amdgcn_mfma_f32_16x16x32_bf16(a1[ks], bfv[fj][ks], acc[2 * q + 1][fj], 0, 0, 0);
        }
      __builtin_amdgcn_s_setprio(0);
    }
    __syncthreads();
  }
#pragma unroll
  for (int fi = 0; fi < 8; ++fi)
#pragma unroll
    for (int fj = 0; fj < 4; ++fj) {
      size_t col = bn + wc * 64 + fj * 16 + fr;
#pragma unroll
      for (int e = 0; e < 4; ++e) {
        size_t r = bm + wr * 128 + fi * 16 + j4 * 4 + e;
        size_t off = r * ldC + col;
        if (BF16OUT) reinterpret_cast<us*>(Cout)[off] = f2b(acc[fi][fj][e]);
        else reinterpret_cast<float*>(Cout)[off] = acc[fi][fj][e];
      }
    }
}

// ---------------- 128^2 GEMM (kept for the tiny ba projection) ----------------
__global__ __launch_bounds__(256) void gemm_lds_f32(const us* __restrict__ A,
    const us* __restrict__ B, float* __restrict__ Cout,
    int K, int Nb1, int Nvalid, int ldC) {
  __shared__ us Ash[128 * 64];
  __shared__ us Bsh[128 * 64];
  int tid = threadIdx.x, w = tid >> 6, lane = tid & 63;
  int bm = blockIdx.x * 128, bn = blockIdx.y * 128;
  int wm = (w >> 1) * 64, wn = (w & 1) * 64;
  const us* aP[4]; const us* bP[4]; us* lA[4]; us* lB[4];
#pragma unroll
  for (int i = 0; i < 4; ++i) {
    int idx = i * 256 + tid;
    int row = idx >> 3;
    int sg = ((idx & 7) ^ (row & 7)) * 8;
    aP[i] = A + (size_t)(bm + row) * K + sg;
    int rb = bn + row; if (rb > Nb1) rb = Nb1;
    bP[i] = B + (size_t)rb * K + sg;
    lA[i] = &Ash[(i * 256 + w * 64) * 8];
    lB[i] = &Bsh[(i * 256 + w * 64) * 8];
  }
  f32x4 acc[4][4] = {};
  int fr = lane & 15, j = lane >> 4;
  for (int kt = 0; kt < K; kt += 64) {
#pragma unroll
    for (int i = 0; i < 4; ++i)
      __builtin_amdgcn_global_load_lds((const void*)(aP[i] + kt), (void*)lA[i], 16, 0, 0);
#pragma unroll
    for (int i = 0; i < 4; ++i)
      __builtin_amdgcn_global_load_lds((const void*)(bP[i] + kt), (void*)lB[i], 16, 0, 0);
    __syncthreads();
#pragma unroll
    for (int ks = 0; ks < 2; ++ks) {
      short8 af[4], bfr[4];
#pragma unroll
      for (int f = 0; f < 4; ++f) {
        int Ra = wm + f * 16 + fr;
        af[f] = *reinterpret_cast<const short8*>(&Ash[Ra * 64 + (((ks * 4 + j) ^ (Ra & 7)) * 8)]);
        int Rb = wn + f * 16 + fr;
        bfr[f] = *reinterpret_cast<const short8*>(&Bsh[Rb * 64 + (((ks * 4 + j) ^ (Rb & 7)) * 8)]);
      }
#pragma unroll
      for (int i = 0; i < 4; ++i)
#pragma unroll
        for (int jj = 0; jj < 4; ++jj)
          acc[i][jj] = __builtin_amdgcn_mfma_f32_16x16x32_bf16(af[i], bfr[jj], acc[i][jj], 0, 0, 0);
    }
    __syncthreads();
  }
#pragma unroll
  for (int i = 0; i < 4; ++i)
#pragma unroll
    for (int jj = 0; jj < 4; ++jj) {
      int c0 = bn + wn + jj * 16 + (lane & 15);
      if (c0 < Nvalid) {
#pragma unroll
        for (int e = 0; e < 4; ++e) {
          int r = bm + wm + i * 16 + (lane >> 4) * 4 + e;
          Cout[(size_t)r * ldC + c0] = acc[i][jj][e];
        }
      }
    }
}

// -------- conv(KC=4)+silu (+l2norm), 4 tokens/block, 8 contiguous channels/thread --------
template <int MODE>
__global__ __launch_bounds__(256) void conv_chunk(const us* __restrict__ mixed,
    const float* __restrict__ cw, us* __restrict__ outp, int headbase) {
  int bp = blockIdx.x, b = bp >> 10, tloc = (bp & 1023) * 4, tid = threadIdx.x;
  int c0 = tid * 8;
  float wv[8][4];
#pragma unroll
  for (int jj = 0; jj < 8; ++jj) {
    float4 w4 = *reinterpret_cast<const float4*>(cw + (size_t)(c0 + jj) * 4);
    wv[jj][0] = w4.x; wv[jj][1] = w4.y; wv[jj][2] = w4.z; wv[jj][3] = w4.w;
  }
  us rw[7][8];
#pragma unroll
  for (int i = 0; i < 7; ++i) {
    int tt = tloc - 3 + i;
    if (tt >= 0 && tt < 4096)
      *reinterpret_cast<uint4*>(rw[i]) = *reinterpret_cast<const uint4*>(
          mixed + ((size_t)(b * 4096 + tt)) * 2048 + c0);
    else
      *reinterpret_cast<uint4*>(rw[i]) = make_uint4(0, 0, 0, 0);
  }
  float x[4][8];
#pragma unroll
  for (int jj = 0; jj < 8; ++jj) {
#pragma unroll
    for (int tk = 0; tk < 4; ++tk) {
      float a = 0.f;
#pragma unroll
      for (int i = 0; i < 4; ++i) a += b2f(rw[tk + i][jj]) * wv[jj][i];
      x[tk][jj] = a / (1.f + __expf(-a));
    }
  }
  size_t bt0 = (size_t)b * 4096 + tloc;
  us ov[8];
  if (MODE < 2) {
    float s[4] = {};
#pragma unroll
    for (int tk = 0; tk < 4; ++tk) {
#pragma unroll
      for (int jj = 0; jj < 8; ++jj) s[tk] += x[tk][jj] * x[tk][jj];
    }
#pragma unroll
    for (int m = 1; m < 16; m <<= 1) {
#pragma unroll
      for (int tk = 0; tk < 4; ++tk) s[tk] += __shfl_xor(s[tk], m, 64);
    }
    const float sc = (MODE == 0 ? 0.08838834764831845f : 1.f);
    int head = tid >> 4, d0 = c0 & 127;
#pragma unroll
    for (int tk = 0; tk < 4; ++tk) {
      float rn = rsqrtf(s[tk] + 1e-6f) * sc;
#pragma unroll
      for (int jj = 0; jj < 8; ++jj) ov[jj] = f2b(x[tk][jj] * rn);
      *reinterpret_cast<uint4*>(outp + ((bt0 + tk) * 16 + head) * 128 + d0) =
          *reinterpret_cast<uint4*>(ov);
    }
  } else {
    int head = headbase + (c0 >> 7), d0 = c0 & 127;
#pragma unroll
    for (int tk = 0; tk < 4; ++tk) {
#pragma unroll
      for (int jj = 0; jj < 8; ++jj) ov[jj] = f2b(x[tk][jj]);
      *reinterpret_cast<uint4*>(outp + ((bt0 + tk) * 32 + head) * 128 + d0) =
          *reinterpret_cast<uint4*>(ov);
    }
  }
}

// -------- gates: beta/g from ba, cumsum g within chunks of 64 --------
__global__ __launch_bounds__(256) void gates_cumsum(const float* __restrict__ ba,
    const float* __restrict__ dt_bias, const float* __restrict__ A_log,
    float* __restrict__ bl_g, float* __restrict__ beta_g) {
  int widx = blockIdx.x * 4 + (threadIdx.x >> 6);
  int lane = threadIdx.x & 63;
  int bh = widx >> 6, chunk = widx & 63;
  int b = bh >> 5, h = bh & 31;
  size_t btl = (size_t)b * 4096 + chunk * 64 + lane;
  float bv = ba[btl * 64 + h];
  float av = ba[btl * 64 + 32 + h];
  float beta = 1.f / (1.f + __expf(-bv));
  float xx = av + dt_bias[h];
  float sp = (xx > 20.f) ? xx : log1pf(__expf(xx));
  float g = -__expf(A_log[h]) * sp;
#pragma unroll
  for (int off = 1; off < 64; off <<= 1) {
    float n = __shfl_up(g, off, 64);
    if (lane >= off) g += n;
  }
  bl_g[(size_t)widx * 64 + lane] = g;
  beta_g[(size_t)widx * 64 + lane] = beta;
}

// ---------------- MFMA tile helpers ----------------
static __device__ __forceinline__ f32x4 tile_range(const us* A, int lda,
    const us* B, int ldb, int rt, int ct, int l0, int nk, int lane, f32x4 acc) {
  const us* ar = A + (rt * 16 + (lane & 15)) * lda + l0 * 16 + (lane >> 4) * 8;
  const us* br = B + (ct * 16 + (lane & 15)) * ldb + l0 * 16 + (lane >> 4) * 8;
#pragma unroll
  for (int ks = 0; ks < nk; ++ks) {
    short8 a = *reinterpret_cast<const short8*>(ar + ks * 32);
    short8 bb = *reinterpret_cast<const short8*>(br + ks * 32);
    acc = __builtin_amdgcn_mfma_f32_16x16x32_bf16(a, bb, acc, 0, 0, 0);
  }
  return acc;
}
// swizzled variant: slot' = slot ^ ((row >> SA/SB) & 7); SA/SB < 0 => no swizzle
template <int SA, int SB>
static __device__ __forceinline__ f32x4 tile_swz(const us* A, int lda,
    const us* B, int ldb, int rt, int ct, int nk, int lane, f32x4 acc) {
  int ra = rt * 16 + (lane & 15);
  int rb = ct * 16 + (lane & 15);
  int j = lane >> 4;
#pragma unroll
  for (int ks = 0; ks < nk; ++ks) {
    int slot = j + 4 * ks;
    int oa = (SA >= 0) ? ((slot ^ ((ra >> (SA < 0 ? 0 : SA)) & 7)) * 8) : (slot * 8);
    int ob = (SB >= 0) ? ((slot ^ ((rb >> (SB < 0 ? 0 : SB)) & 7)) * 8) : (slot * 8);
    short8 a = *reinterpret_cast<const short8*>(A + ra * lda + oa);
    short8 bb = *reinterpret_cast<const short8*>(B + rb * ldb + ob);
    acc = __builtin_amdgcn_mfma_f32_16x16x32_bf16(a, bb, acc, 0, 0, 0);
  }
  return acc;
}

// =======================================================================
// Scan pass 1 (chunk-parallel): per (bh, chunk) compute T=(I+D)^-1 -> Tg.
// =======================================================================
__global__ __launch_bounds__(512, 1) void scan_p1(
    const us* __restrict__ k, const float* __restrict__ bl_g,
    const float* __restrict__ beta_g, us* __restrict__ Tg) {
  __shared__ us Kb[64 * 136];
  __shared__ us Ebt[64 * 72];
  __shared__ us W1[64 * 72], W1t[64 * 72], W3[64 * 72];
  __shared__ float bl_s[64], bet_s[64];
  us* const Eb = Kb;

  int bid = blockIdx.x, bh = bid >> 6, c = bid & 63;
  int b = bh >> 5, h = bh & 31, hk = h >> 1;
  int tid = threadIdx.x, w = tid >> 6, lane = tid & 63;
  int row = tid >> 3, c16 = (tid & 7) * 16;
  size_t bt0 = (size_t)b * 4096 + c * 64;

  const int TR_[10] = {0, 1, 1, 2, 2, 2, 3, 3, 3, 3};
  const int TC_[10] = {0, 0, 1, 0, 1, 2, 0, 1, 2, 3};

  const us* kp = k + ((bt0 + row) * 16 + hk) * 128 + c16;
  uint4 kr0 = reinterpret_cast<const uint4*>(kp)[0];
  uint4 kr1 = reinterpret_cast<const uint4*>(kp)[1];
  int gbase = (bh * 64 + c) * 64;
  if (tid < 64) { bl_s[tid] = bl_g[gbase + tid]; bet_s[tid] = beta_g[gbase + tid]; }
  *reinterpret_cast<uint4*>(&Kb[row * 136 + c16]) = kr0;
  *reinterpret_cast<uint4*>(&Kb[row * 136 + c16 + 8]) = kr1;
  __syncthreads();
  {
    int art = w & 3;
#pragma unroll
    for (int s = 0; s < 2; ++s) {
      int ct = (w >> 2) * 2 + s;
      f32x4 a = tile_range(Kb, 136, Kb, 136, art, ct, 0, 4, lane, f32x4{});
#pragma unroll
      for (int e = 0; e < 4; ++e) {
        int tr = art * 16 + (lane >> 4) * 4 + e;
        int cl = ct * 16 + (lane & 15);
        float dv = (cl < tr) ? bet_s[tr] * __expf(bl_s[tr] - bl_s[cl]) * a[e] : 0.f;
        W1[tr * 72 + cl] = f2b(dv);
        W1t[cl * 72 + tr] = f2b(dv);
        W3[tr * 72 + cl] = f2b((tr == cl ? 1.f : 0.f) - dv);
      }
    }
  }
  __syncthreads();
  f32x4 freg[2] = {};
#pragma unroll
  for (int it = 1; it <= 5; ++it) {
    if (it > 1) {
#pragma unroll
      for (int s = 0; s < 2; ++s) {
        int j = w + s * 8;
        if (j < 10) {
          int r = TR_[j], cc0 = TC_[j];
#pragma unroll
          for (int e = 0; e < 4; ++e) {
            int rr = r * 16 + (lane >> 4) * 4 + e, cl = cc0 * 16 + (lane & 15);
            W3[rr * 72 + cl] = f2b(b2f(W3[rr * 72 + cl]) + freg[s][e]);
          }
        }
      }
    }
    if (it == 1) {
      const int ZR[12] = {0, 0, 0, 1, 1, 2, 1, 2, 2, 3, 3, 3};
      const int ZC[12] = {1, 2, 3, 2, 3, 3, 0, 0, 1, 0, 1, 2};
#pragma unroll
      for (int u = 0; u < 12; ++u) {
        if ((u & 7) != w) continue;
        us* arr = (u < 6) ? Eb : Ebt;
        if (lane < 32) {
          int rr = ZR[u] * 16 + (lane >> 1);
          *reinterpret_cast<uint4*>(&arr[rr * 72 + ZC[u] * 16 + (lane & 1) * 8]) =
              make_uint4(0, 0, 0, 0);
        }
      }
    }
    const us* Es  = (it & 1) ? W1  : Eb;
    const us* Est = (it & 1) ? W1t : Ebt;
    us* Ed  = (it & 1) ? Eb  : W1;
    us* Edt = (it & 1) ? Ebt : W1t;
#pragma unroll
    for (int s = 0; s < 2; ++s) {
      int j = w + s * 8;
      if (j < 10) {
        int r = TR_[j], cc0 = TC_[j];
        int l0 = cc0 & ~1, nk = (r - l0 + 2) >> 1;
        f32x4 a = tile_range(Es, 72, Est, 72, r, cc0, l0, nk, lane, f32x4{});
#pragma unroll
        for (int e = 0; e < 4; ++e) {
          int rr = r * 16 + (lane >> 4) * 4 + e, cl = cc0 * 16 + (lane & 15);
          us val = f2b(a[e]);
          Ed[rr * 72 + cl] = val;
          Edt[cl * 72 + rr] = val;
        }
      }
    }
    __syncthreads();
    const us* Ent = (it & 1) ? Ebt : W1t;
#pragma unroll
    for (int s = 0; s < 2; ++s) {
      int j = w + s * 8;
      if (j < 10) {
        int r = TR_[j], cc0 = TC_[j];
        int l0 = cc0 & ~1, nk = (r - l0 + 2) >> 1;
        freg[s] = tile_range(W3, 72, Ent, 72, r, cc0, l0, nk, lane, f32x4{});
      }
    }
    __syncthreads();
  }
#pragma unroll
  for (int s = 0; s < 2; ++s) {
    int j = w + s * 8;
    if (j < 10) {
      int r = TR_[j], cc0 = TC_[j];
#pragma unroll
      for (int e = 0; e < 4; ++e) {
        int rr = r * 16 + (lane >> 4) * 4 + e, cl = cc0 * 16 + (lane & 15);
        W3[rr * 72 + cl] = f2b(b2f(W3[rr * 72 + cl]) + freg[s][e]);
      }
    }
  }
  __syncthreads();
  *reinterpret_cast<uint4*>(&Tg[(size_t)bid * 4096 + tid * 8]) =
      *reinterpret_cast<const uint4*>(&W3[row * 72 + (tid & 7) * 8]);
}

// =======================================================================
// Scan pass 2: sequential over chunks, 4x V-split (256 blocks).
// 3 barriers/chunk (LF merged into OS); gates double-buffered.
// o may alias v: each block touches only columns [vs*32, vs*32+32) of its
// own head h in both, and reads of chunk c+2 precede writes of chunk c.
// =======================================================================
__global__ __launch_bounds__(512, 1) void scan_p2(
    const us* __restrict__ q, const us* __restrict__ k, const us* __restrict__ v,
    const float* __restrict__ bl_g, const float* __restrict__ beta_g,
    const us* __restrict__ Tg, us* __restrict__ o) {
  __shared__ us Sb[32 * 136];
  __shared__ us Kb[64 * 136];
  __shared__ us Qb[64 * 136];
  __shared__ us Ktb[128 * 72];   // e^{bC-b_t} K^T [d][t], slot ^ (d>>4)
  __shared__ us Vt[32 * 72];     // [v][t], slot ^ (v>>3)
  __shared__ us Ut[32 * 72];     // [v][t], slot ^ (v>>3)
  __shared__ us W3[64 * 72];
  __shared__ us WP[64 * 72];
  __shared__ float bl_s[2][64], bet_s[2][64], ksc_s[2][64];

  int bid = blockIdx.x, vs = bid >> 6, bh = bid & 63;
  int b = bh >> 5, h = bh & 31, hk = h >> 1;
  int tid = threadIdx.x, w = tid >> 6, lane = tid & 63;
  int row = tid >> 3, c16 = (tid & 7) * 16;

  for (int i = tid; i < (32 * 136) / 8; i += 512)
    reinterpret_cast<uint4*>(Sb)[i] = make_uint4(0, 0, 0, 0);

  uint4 kr0, kr1, qr0, qr1, vr, Tr;
  float blr, blC, bet, betv;
  int vrow = (tid & 255) >> 2, vseg = tid & 3;
  auto load_regs = [&](int c) {
    size_t bt0 = (size_t)b * 4096 + c * 64;
    const us* kp = k + ((bt0 + row) * 16 + hk) * 128 + c16;
    const us* qp = q + ((bt0 + row) * 16 + hk) * 128 + c16;
    kr0 = reinterpret_cast<const uint4*>(kp)[0];
    kr1 = reinterpret_cast<const uint4*>(kp)[1];
    qr0 = reinterpret_cast<const uint4*>(qp)[0];
    qr1 = reinterpret_cast<const uint4*>(qp)[1];
    Tr = *reinterpret_cast<const uint4*>(&Tg[((size_t)bh * 64 + c) * 4096 + tid * 8]);
    int gbase = (bh * 64 + c) * 64;
    blr = bl_g[gbase + row];
    blC = bl_g[gbase + 63];
    bet = beta_g[gbase + row];
    if (tid < 256) {
      vr = *reinterpret_cast<const uint4*>(
          v + ((bt0 + vrow) * 32 + h) * 128 + vs * 32 + vseg * 8);
      betv = beta_g[gbase + vrow];
    }
  };
  auto lf_write = [&](int cc) {
    int pcw = cc & 1;
    if ((tid & 7) == 0) {
      bl_s[pcw][row] = blr; bet_s[pcw][row] = bet;
      ksc_s[pcw][row] = __expf(blC - blr);
    }
    *reinterpret_cast<uint4*>(&Kb[row * 136 + c16]) = kr0;
    *reinterpret_cast<uint4*>(&Kb[row * 136 + c16 + 8]) = kr1;
    *reinterpret_cast<uint4*>(&Qb[row * 136 + c16]) = qr0;
    *reinterpret_cast<uint4*>(&Qb[row * 136 + c16 + 8]) = qr1;
    *reinterpret_cast<uint4*>(&W3[row * 72 + (tid & 7) * 8]) = Tr;
    if (tid < 256) {
      us vreg[8];
      *reinterpret_cast<uint4*>(vreg) = vr;
#pragma unroll
      for (int i = 0; i < 8; ++i) {
        int vv = vseg * 8 + i;
        Vt[vv * 72 + (((vrow >> 3) ^ vseg) & 7) * 8 + (vrow & 7)] = f2b(betv * b2f(vreg[i]));
      }
    }
  };

  load_regs(0);
  lf_write(0);
  load_regs(1);
  bar_lds();  // publishes Sb init + LF(0)

  for (int c = 0; c < 64; ++c) {
    int pc = c & 1;
    size_t bt0 = (size_t)b * 4096 + c * 64;
    // ---- G1: Ktb build + Q.S0 + P + RHS ----
#pragma unroll
    for (int tk = 0; tk < 2; ++tk) {
      int task = tid + tk * 512;
      int d = task & 127, oct = task >> 7;
      us kt[8];
#pragma unroll
      for (int i = 0; i < 8; ++i)
        kt[i] = f2b(ksc_s[pc][oct * 8 + i] * b2f(Kb[(oct * 8 + i) * 136 + d]));
      *reinterpret_cast<uint4*>(&Ktb[d * 72 + ((oct ^ ((d >> 4) & 7)) * 8)]) =
          *reinterpret_cast<uint4*>(kt);
    }
    int rtO = w >> 1, ctv = w & 1;
    f32x4 o1 = tile_swz<-1, -1>(Qb, 136, Sb, 136, rtO, ctv, 4, lane, f32x4{});
    {
      int art = w & 3;
#pragma unroll
      for (int s = 0; s < 2; ++s) {
        int ct = (w >> 2) * 2 + s;
        f32x4 a = tile_swz<-1, -1>(Qb, 136, Kb, 136, art, ct, 4, lane, f32x4{});
#pragma unroll
        for (int e = 0; e < 4; ++e) {
          int tr = art * 16 + (lane >> 4) * 4 + e;
          int cl = ct * 16 + (lane & 15);
          float pv = (cl <= tr) ? __expf(bl_s[pc][tr] - bl_s[pc][cl]) * a[e] : 0.f;
          WP[tr * 72 + cl] = f2b(pv);
        }
      }
    }
    {
      int vrt = w >> 2, ct = w & 3;
      f32x4 a = tile_swz<-1, -1>(Sb, 136, Kb, 136, vrt, ct, 4, lane, f32x4{});
      int tt = ct * 16 + (lane & 15);
      float csc = bet_s[pc][tt] * __expf(bl_s[pc][tt]);
#pragma unroll
      for (int e = 0; e < 4; ++e) {
        int vv = vrt * 16 + (lane >> 4) * 4 + e;
        int off = vv * 72 + (((tt >> 3) ^ ((vv >> 3) & 7)) * 8) + (tt & 7);
        Vt[off] = f2b(b2f(Vt[off]) - csc * a[e]);
      }
    }
    bar_lds();
    // ---- G2: Ut = RHS^T . T^T ----
    {
      int vrt = w >> 2, ct = w & 3;
      f32x4 a = tile_swz<3, -1>(Vt, 72, W3, 72, vrt, ct, 2, lane, f32x4{});
#pragma unroll
      for (int e = 0; e < 4; ++e) {
        int uv = vrt * 16 + (lane >> 4) * 4 + e;
        int ut2 = ct * 16 + (lane & 15);
        Ut[uv * 72 + (((ut2 >> 3) ^ ((uv >> 3) & 7)) * 8) + (ut2 & 7)] = f2b(a[e]);
      }
    }
    bar_lds();
    // ---- OS: O write + S update, overlapped with LF(c+1) ----
    float lamC = __expf(bl_s[pc][63]);
    {
      f32x4 a = tile_swz<-1, 3>(WP, 72, Ut, 72, rtO, ctv, 2, lane, f32x4{});
#pragma unroll
      for (int e = 0; e < 4; ++e) {
        int tt = rtO * 16 + (lane >> 4) * 4 + e;
        int vv = vs * 32 + ctv * 16 + (lane & 15);
        float val = __expf(bl_s[pc][tt]) * o1[e] + a[e];
        o[((bt0 + tt) * 32 + h) * 128 + vv] = f2b(val);
      }
    }
#pragma unroll
    for (int s = 0; s < 2; ++s) {
      int ti = w * 2 + s;
      int vrt = ti >> 3, dt = ti & 7;
      f32x4 a = tile_swz<3, 4>(Ut, 72, Ktb, 72, vrt, dt, 2, lane, f32x4{});
#pragma unroll
      for (int e = 0; e < 4; ++e) {
        int vv = vrt * 16 + (lane >> 4) * 4 + e, dd = dt * 16 + (lane & 15);
        Sb[vv * 136 + dd] = f2b(lamC * b2f(Sb[vv * 136 + dd]) + a[e]);
      }
    }
    if (c < 63) {
      lf_write(c + 1);
      load_regs(c + 2 <= 63 ? c + 2 : 63);
    }
    bar_lds();
  }
}

// ---------------- gated RMSNorm, in place, vectorized ----------------
__global__ __launch_bounds__(256) void rms_gate(us* oy,
    const us* __restrict__ z, const float* __restrict__ nw) {
  int sub = threadIdx.x & 31;
  size_t row = (size_t)blockIdx.x * 8 + (threadIdx.x >> 5);
  size_t base = row * 128 + sub * 4;
  ushort4 ov = *reinterpret_cast<ushort4*>(oy + base);
  ushort4 zv = *reinterpret_cast<const ushort4*>(z + base);
  float o_[4] = {b2f(ov.x), b2f(ov.y), b2f(ov.z), b2f(ov.w)};
  float ss = o_[0] * o_[0] + o_[1] * o_[1] + o_[2] * o_[2] + o_[3] * o_[3];
#pragma unroll
  for (int m = 1; m < 32; m <<= 1) ss += __shfl_xor(ss, m, 64);
  float r = rsqrtf(ss * (1.f / 128.f) + 1e-6f);
  float4 w4 = *reinterpret_cast<const float4*>(nw + sub * 4);
  float zz[4] = {b2f(zv.x), b2f(zv.y), b2f(zv.z), b2f(zv.w)};
  float wv[4] = {w4.x, w4.y, w4.z, w4.w};
  us res[4];
#pragma unroll
  for (int i = 0; i < 4; ++i) {
    float zs = zz[i] / (1.f + __expf(-zz[i]));
    res[i] = f2b(o_[i] * r * wv[i] * zs);
  }
  *reinterpret_cast<ushort4*>(oy + base) = *reinterpret_cast<ushort4*>(res);
}

extern "C" void kernel_launch(void* const* d_in, const int* in_sizes, int n_in,
                              void* d_out, int out_size, void* d_ws, size_t ws_size,
                              hipStream_t stream) {
  const float* hs      = (const float*)d_in[0];
  const float* W_qkv   = (const float*)d_in[1];
  const float* W_z     = (const float*)d_in[2];
  const float* W_b     = (const float*)d_in[3];
  const float* W_a     = (const float*)d_in[4];
  const float* conv_w  = (const float*)d_in[5];
  const float* dt_bias = (const float*)d_in[6];
  const float* A_log   = (const float*)d_in[7];
  const float* norm_w  = (const float*)d_in[8];
  const float* W_out   = (const float*)d_in[9];
  float* out = (float*)d_out;

  char* ws = (char*)d_ws;
  const size_t MiB = 1u << 20;
  // layout (MiB), peak 228 (proven safe):
  //  0-2 ba | 2-3 bl | 3-4 bt
  //  4-36: W_qkv^T -> Tg (scan) \__ 4-68: z (post-scan)
  //  36-68: mixed / wt_sm       /
  //  68-100: hs_bf0 (alive through the whole pipeline; no regen)
  //  100-132: q -> W_z^T / W_out^T (post-scan)
  //  132-164: k | 164-228: v == o (aliased; disjoint per-block slices)
  float* ba_buf = (float*)(ws);
  float* bl_g   = (float*)(ws + 2 * MiB);
  float* bt_g   = (float*)(ws + 3 * MiB);
  us*    wt     = (us*)(ws + 4 * MiB);
  us*    Tg     = (us*)(ws + 4 * MiB);
  us*    z_bf   = (us*)(ws + 4 * MiB);
  us*    mixed  = (us*)(ws + 36 * MiB);
  us*    wt_sm  = (us*)(ws + 36 * MiB);
  us*    hs_bf0 = (us*)(ws + 68 * MiB);
  us*    q_buf  = (us*)(ws + 100 * MiB);
  us*    wt2    = (us*)(ws + 100 * MiB);
  us*    k_buf  = (us*)(ws + 132 * MiB);
  us*    v_buf  = (us*)(ws + 164 * MiB);
  us*    o_buf  = v_buf;  // o aliases v

  cvt_f32_bf16<<<2048, 256, 0, stream>>>(hs, hs_bf0, (long)8192 * 2048 / 4);

  // full W_qkv^T in one dispatch (into 4-36, dead until scan_p1 writes Tg)
  transpose_cvt<<<dim3(128, 32), 256, 0, stream>>>(W_qkv, wt, 2048, 8192, 8192, 0, 0);
  for (int c = 0; c < 4; ++c) {
    gemm256<true><<<dim3(32, 8), 512, 0, stream>>>(
        hs_bf0, wt + (size_t)c * 2048 * 2048, mixed, 2048, 2048);
    const float* cwc = conv_w + (size_t)c * 2048 * 4;
    if (c == 0)      conv_chunk<0><<<2048, 256, 0, stream>>>(mixed, cwc, q_buf, 0);
    else if (c == 1) conv_chunk<1><<<2048, 256, 0, stream>>>(mixed, cwc, k_buf, 0);
    else if (c == 2) conv_chunk<2><<<2048, 256, 0, stream>>>(mixed, cwc, v_buf, 0);
    else             conv_chunk<2><<<2048, 256, 0, stream>>>(mixed, cwc, v_buf, 16);
  }
  // beta/a projections (tiny W^T into dead mixed region) + gates
  transpose_cvt<<<dim3(1, 32), 256, 0, stream>>>(W_b, wt_sm, 2048, 32, 32, 0, 0);
  transpose_cvt<<<dim3(1, 32), 256, 0, stream>>>(W_a, wt_sm, 2048, 32, 32, 0, 32);
  gemm_lds_f32<<<dim3(64, 1), 256, 0, stream>>>(hs_bf0, wt_sm, ba_buf, 2048, 63, 64, 64);
  gates_cumsum<<<1024, 256, 0, stream>>>(ba_buf, dt_bias, A_log, bl_g, bt_g);
  // two-pass chunked delta-rule scan (o aliases v)
  scan_p1<<<4096, 512, 0, stream>>>(k_buf, bl_g, bt_g, Tg);
  scan_p2<<<256, 512, 0, stream>>>(q_buf, k_buf, v_buf, bl_g, bt_g, Tg, o_buf);
  // z projection: hs_bf0 still alive; W_z^T into dead q region; z into 4-68
  transpose_cvt<<<dim3(64, 32), 256, 0, stream>>>(W_z, wt2, 2048, 4096, 4096, 0, 0);
  gemm256<true><<<dim3(32, 16), 512, 0, stream>>>(hs_bf0, wt2, z_bf, 2048, 4096);
  rms_gate<<<32768, 256, 0, stream>>>(o_buf, z_bf, norm_w);
  // output projection
  transpose_cvt<<<dim3(32, 64), 256, 0, stream>>>(W_out, wt2, 4096, 2048, 2048, 0, 0);
  gemm256<false><<<dim3(32, 8), 512, 0, stream>>>(o_buf, wt2, out, 4096, 2048);
}